// Round 21
// baseline (309.802 us; speedup 1.0000x reference)
//
#include <hip/hip_runtime.h>
#include <hip/hip_fp16.h>

#define NPOS   4096
#define CDIM   512
#define CQK    64
#define NBATCH 4
#define L2E 1.44269504088896f

typedef _Float16 f16x8 __attribute__((ext_vector_type(8)));
typedef _Float16 f16x4 __attribute__((ext_vector_type(4)));
typedef float    f32x4 __attribute__((ext_vector_type(4)));

// ---------------- x convert+transpose (+ fused weight convert) ----------------
// (R20 structure — measured best; unchanged.)
__global__ __launch_bounds__(256) void x_cvt_kernel(
    const float* __restrict__ x, _Float16* __restrict__ Xt,
    const float* __restrict__ wq, const float* __restrict__ bq,
    const float* __restrict__ wk, const float* __restrict__ bk,
    const float* __restrict__ wv, const float* __restrict__ bv,
    _Float16* __restrict__ Wh, float* __restrict__ biasc)
{
    __shared__ _Float16 tile[64][66];
    const int b  = blockIdx.z;
    const int c0 = blockIdx.y * 64;
    const int n0 = blockIdx.x * 64;
    const int tid = threadIdx.x;

    if (blockIdx.z == 0 && blockIdx.y == 0) {
        const int gid = blockIdx.x * 256 + tid;          // 0..16383
#pragma unroll 1
        for (int idx4 = gid; idx4 < 640 * CDIM / 4; idx4 += 64 * 256) {
            const int idx = idx4 * 4;
            const float* src;
            if (idx < 64 * 512)       src = wq + idx;
            else if (idx < 128 * 512) src = wk + (idx - 64 * 512);
            else                      src = wv + (idx - 128 * 512);
            const float4 v = *reinterpret_cast<const float4*>(src);
            f16x4 h;
            h[0] = (_Float16)v.x; h[1] = (_Float16)v.y;
            h[2] = (_Float16)v.z; h[3] = (_Float16)v.w;
            *reinterpret_cast<f16x4*>(Wh + idx) = h;
        }
        if (gid < 640) {
            float bb;
            if (gid < 64)       bb = bq[gid];
            else if (gid < 128) bb = bk[gid - 64];
            else                bb = bv[gid - 128];
            biasc[gid] = bb;
        }
    }

    const int rr = tid >> 4;
    const int n4 = (tid & 15) * 4;
#pragma unroll
    for (int i = 0; i < 4; ++i) {
        const int c = i * 16 + rr;
        const float4 v = *reinterpret_cast<const float4*>(
            x + (size_t)(b * CDIM + c0 + c) * NPOS + n0 + n4);
        tile[c][n4 + 0] = (_Float16)v.x;
        tile[c][n4 + 1] = (_Float16)v.y;
        tile[c][n4 + 2] = (_Float16)v.z;
        tile[c][n4 + 3] = (_Float16)v.w;
    }
    __syncthreads();

    const int col = tid & 63;
    const int r4  = tid >> 6;
#pragma unroll
    for (int i = 0; i < 16; ++i) {
        const int n = i * 4 + r4;
        Xt[((size_t)b * NPOS + n0 + n) * CDIM + c0 + col] = tile[col][n];
    }
}

// ---------------- fused QKV projection GEMM: 128x128 tile, LDS double-buffered ----------------
// (R13 structure — measured best; unchanged.)
__global__ __launch_bounds__(256) void proj_gemm_kernel(
    const _Float16* __restrict__ Wh, const float* __restrict__ biasc,
    const _Float16* __restrict__ Xt,
    _Float16* __restrict__ Qp, _Float16* __restrict__ Kp, _Float16* __restrict__ Vp)
{
    __shared__ __align__(16) _Float16 As[2][128 * 32];
    __shared__ __align__(16) _Float16 Bs[2][128 * 32];

    const int tid  = threadIdx.x;
    const int lane = tid & 63;
    const int w    = tid >> 6;       // 0..3
    const int wr   = w >> 1;         // m-half
    const int wc   = w & 1;          // n-half
    const int g    = lane >> 4;
    const int lr   = lane & 15;

    const int b  = blockIdx.z;
    const int m0 = blockIdx.y * 128;
    const int n0 = blockIdx.x * 128;

    const _Float16* xb = Xt + (size_t)b * NPOS * CDIM;

    const int srow = tid >> 2;
    const int schk = (tid & 3) * 8;

    f16x8 sA[2], sB[2];
    auto gload = [&](int kk) {
#pragma unroll
        for (int rnd = 0; rnd < 2; ++rnd) {
            const int row = srow + rnd * 64;
            sA[rnd] = *reinterpret_cast<const f16x8*>(
                Wh + (size_t)(m0 + row) * CDIM + kk + schk);
            sB[rnd] = *reinterpret_cast<const f16x8*>(
                xb + (size_t)(n0 + row) * CDIM + kk + schk);
        }
    };
    auto dswrite = [&](int buf) {
#pragma unroll
        for (int rnd = 0; rnd < 2; ++rnd) {
            const int row = srow + rnd * 64;
            *reinterpret_cast<f16x8*>(&As[buf][row * 32 + schk]) = sA[rnd];
            *reinterpret_cast<f16x8*>(&Bs[buf][row * 32 + schk]) = sB[rnd];
        }
    };

    f32x4 acc[4][4];
#pragma unroll
    for (int it = 0; it < 4; ++it)
#pragma unroll
        for (int ct = 0; ct < 4; ++ct) {
            f32x4 z = {0.f, 0.f, 0.f, 0.f};
            acc[it][ct] = z;
        }

    auto compute = [&](int buf) {
        f16x8 a[4], bf[4];
#pragma unroll
        for (int it = 0; it < 4; ++it)
            a[it] = *reinterpret_cast<const f16x8*>(
                &As[buf][(wr * 64 + it * 16 + lr) * 32 + 8 * g]);
#pragma unroll
        for (int ct = 0; ct < 4; ++ct)
            bf[ct] = *reinterpret_cast<const f16x8*>(
                &Bs[buf][(wc * 64 + ct * 16 + lr) * 32 + 8 * g]);
#pragma unroll
        for (int it = 0; it < 4; ++it)
#pragma unroll
            for (int ct = 0; ct < 4; ++ct)
                acc[it][ct] = __builtin_amdgcn_mfma_f32_16x16x32_f16(a[it], bf[ct], acc[it][ct], 0, 0, 0);
    };

    gload(0);
    dswrite(0);
    __syncthreads();

#pragma unroll 1
    for (int t = 0; t < 16; ++t) {
        if (t < 15) gload((t + 1) * 32);
        compute(t & 1);
        if (t < 15) dswrite((t + 1) & 1);
        __syncthreads();
    }

    if (m0 == 0) {
        _Float16* dst = (wr == 0) ? Qp : Kp;
#pragma unroll
        for (int it = 0; it < 4; ++it) {
            const int gmb = m0 + wr * 64 + it * 16 + 4 * g;
            const int ob  = gmb & 63;
#pragma unroll
            for (int ct = 0; ct < 4; ++ct) {
                const int n = n0 + wc * 64 + ct * 16 + lr;
                f16x4 h;
#pragma unroll
                for (int r = 0; r < 4; ++r)
                    h[r] = (_Float16)(acc[it][ct][r] + biasc[gmb + r]);
                *reinterpret_cast<f16x4*>(dst + ((size_t)b * NPOS + n) * CQK + ob) = h;
            }
        }
    } else {
#pragma unroll
        for (int it = 0; it < 4; ++it) {
            const int gmb = m0 + wr * 64 + it * 16 + 4 * g;
#pragma unroll
            for (int ct = 0; ct < 4; ++ct) {
                const int n = n0 + wc * 64 + ct * 16 + lr;
#pragma unroll
                for (int r = 0; r < 4; ++r) {
                    const int c = gmb + r - 128;
                    Vp[((size_t)b * CDIM + c) * NPOS + n] =
                        (_Float16)(acc[it][ct][r] + biasc[gmb + r]);
                }
            }
        }
    }
}

// ---------------- Fused attention: REGISTER-P flash (no barriers in main loop) ----------------
// Pass 1: unchanged (row max, swapped chain, 8-wave sliced, LDS reduce).
// Pass 2 (NEW): each wave computes E for the FULL 128-j chunk (all 8 j-tiles), keeps
// P in registers (f16 pairs), and feeds PV's A-operand directly via a fixed cross-lane
// regroup: swapped-E D-layout gives lane (g,lr) -> P[i=lr][j=4g+r]; A-frag needs lane
// (g',lr) -> P[i=lr][k=8g'+t]. Same row owner (lr) -> word w of the A-frag comes from
// src lane 16*(2*(g'&1)+(w>>1))+lr, src pack word w&1, pk-set (g'>>1) <=> lane<32.
// Implemented as 2x ds_bpermute + select per 4B word. NO LDS P tile, NO __syncthreads
// in the main loop -> the 8 waves drift freely (the barrier rendezvous was the measured
// ~90% stall across 12 prior experiments). E work is 8x (all waves all j) but MFMA has
// ~10x headroom; K re-reads are L1-absorbed (all 8 waves read the same 16KB chunk).
// l is accumulated only for jt==w (each j counted exactly once globally). E chains,
// global m, and f16-RTE P are bit-identical to R18-20 -> acc bitwise identical ->
// absmax must be exactly 0.03125 (built-in correctness probe).
// launch_bounds (512,1): allocator-budget hypothesis 256/min_waves (measured: (*,4)->64,
// (*,2)->128); live set ~206 VGPR; 8 waves/CU retained for VGPR<=256 (m69 occupancy).
__global__ __launch_bounds__(512, 1) void attn_fused_kernel(
    const float* __restrict__ x, const _Float16* __restrict__ Qp, const _Float16* __restrict__ Kp,
    const _Float16* __restrict__ Vp, const float* __restrict__ gamma, float* __restrict__ out)
{
    __shared__ float lmw[8 * 64];
    __shared__ float mfin[64];
    __shared__ float lfin[64];

    const int tid  = threadIdx.x;
    const int lane = tid & 63;
    const int w    = tid >> 6;      // 0..7
    const int g    = lane >> 4;     // 0..3
    const int lr   = lane & 15;

    // XCD-aware decode: batch b -> XCDs {2b,2b+1} so each XCD L2 holds one batch's V+K.
    const int bid = blockIdx.x;
    const int b   = (bid & 7) >> 1;
    const int ib  = (((bid >> 3) << 1) | (bid & 1)) * 64;
    const int cw  = w * 64;

    const _Float16* kb = Kp + (size_t)b * NPOS * CQK;
    const _Float16* vb = Vp + (size_t)b * CDIM * NPOS;

    f16x8 qf[4][2];
#pragma unroll
    for (int it = 0; it < 4; ++it)
#pragma unroll
        for (int ks = 0; ks < 2; ++ks)
            qf[it][ks] = *reinterpret_cast<const f16x8*>(
                Qp + (b * NPOS + ib + it * 16 + lr) * CQK + ks * 32 + 8 * g);

    // ======== PASS 1: row max only (R18 structure, unchanged) ========
    {
        f16x8 kA0, kA1, kB0, kB1;
        auto loadK = [&](int t, f16x8& k0, f16x8& k1) {
            const int tc = (t < 32) ? t : 31;
            const int j = tc * 128 + w * 16 + lr;
            k0 = *reinterpret_cast<const f16x8*>(kb + j * CQK + 8 * g);
            k1 = *reinterpret_cast<const f16x8*>(kb + j * CQK + 32 + 8 * g);
        };
        float mrun[4];
#pragma unroll
        for (int it = 0; it < 4; ++it) mrun[it] = -1e30f;

        auto step = [&](const f16x8& k0, const f16x8& k1) {
#pragma unroll
            for (int it = 0; it < 4; ++it) {
                f32x4 e = {0.f, 0.f, 0.f, 0.f};
                e = __builtin_amdgcn_mfma_f32_16x16x32_f16(k0, qf[it][0], e, 0, 0, 0);
                e = __builtin_amdgcn_mfma_f32_16x16x32_f16(k1, qf[it][1], e, 0, 0, 0);
                mrun[it] = fmaxf(mrun[it],
                                 fmaxf(fmaxf(e[0], e[1]), fmaxf(e[2], e[3])));
            }
        };

        loadK(0, kA0, kA1);
#pragma unroll 1
        for (int tp = 0; tp < 16; ++tp) {
            const int t = 2 * tp;
            loadK(t + 1, kB0, kB1);
            step(kA0, kA1);
            loadK(t + 2, kA0, kA1);
            step(kB0, kB1);
        }

#pragma unroll
        for (int it = 0; it < 4; ++it) {
            float m = mrun[it];
#pragma unroll
            for (int mask = 16; mask < 64; mask <<= 1)
                m = fmaxf(m, __shfl_xor(m, mask, 64));
            if (g == 0)
                lmw[w * 64 + it * 16 + lr] = m;
        }
        __syncthreads();

        if (tid < 64) {
            float mm = lmw[tid];
#pragma unroll
            for (int w2 = 1; w2 < 8; ++w2) mm = fmaxf(mm, lmw[w2 * 64 + tid]);
            mfin[tid] = mm;
        }
        __syncthreads();
    }

    float mreg[4];
#pragma unroll
    for (int it = 0; it < 4; ++it)
        mreg[it] = mfin[it * 16 + lr];

    // ======== PASS 2: register-P flash, no barriers ========
    f32x4 acc[4][4];
#pragma unroll
    for (int it = 0; it < 4; ++it)
#pragma unroll
        for (int ct = 0; ct < 4; ++ct) {
            f32x4 z = {0.f, 0.f, 0.f, 0.f};
            acc[it][ct] = z;
        }

    float lrun[4] = {0.f, 0.f, 0.f, 0.f};
    f16x8 vreg[4][4];   // full-chunk V (64 VGPR), reloaded once per chunk

    auto loadV = [&](int t) {
        const int jb = t * 128;
#pragma unroll
        for (int ks = 0; ks < 4; ++ks)
#pragma unroll
            for (int ct = 0; ct < 4; ++ct)
                vreg[ks][ct] = *reinterpret_cast<const f16x8*>(
                    vb + (size_t)(cw + ct * 16 + lr) * NPOS + jb + ks * 32 + 8 * g);
    };

    // K tile stream: s = t*8 + jt  (j = s*16 + lr), 2 slots, parity(s) = jt&1.
    f16x8 k0s[2], k1s[2];
    auto loadKs = [&](int s, int slot) {
        const int sc = (s < 256) ? s : 255;
        const _Float16* p = kb + (size_t)(sc * 16 + lr) * CQK + 8 * g;
        k0s[slot] = *reinterpret_cast<const f16x8*>(p);
        k1s[slot] = *reinterpret_cast<const f16x8*>(p + 32);
    };

    // bpermute source-lane byte indices (w<2 -> idxA, w>=2 -> idxB)
    const int idxA = ((2 * (g & 1) + 0) * 16 + lr) * 4;
    const int idxB = ((2 * (g & 1) + 1) * 16 + lr) * 4;

    uint32_t pk[2][4][2];   // [jtl][it][word] : P packed as f16 pairs (j even, j odd)

    loadKs(0, 0);
    loadKs(1, 1);

#pragma unroll 1
    for (int t = 0; t < 32; ++t) {
        loadV(t);   // WAR on vreg: issued after chunk t-1's last PV consumed it
#pragma unroll
        for (int ksb = 0; ksb < 4; ++ksb) {
            // ---- E for j-tiles 2ksb, 2ksb+1 (slot = jtl, parity-consistent) ----
#pragma unroll
            for (int jtl = 0; jtl < 2; ++jtl) {
                const int jt = 2 * ksb + jtl;
                const int s  = t * 8 + jt;
#pragma unroll
                for (int it = 0; it < 4; ++it) {
                    f32x4 e = {0.f, 0.f, 0.f, 0.f};
                    e = __builtin_amdgcn_mfma_f32_16x16x32_f16(k0s[jtl], qf[it][0], e, 0, 0, 0);
                    e = __builtin_amdgcn_mfma_f32_16x16x32_f16(k1s[jtl], qf[it][1], e, 0, 0, 0);
                    _Float16 p0 = (_Float16)exp2f((e[0] - mreg[it]) * L2E);
                    _Float16 p1 = (_Float16)exp2f((e[1] - mreg[it]) * L2E);
                    _Float16 p2 = (_Float16)exp2f((e[2] - mreg[it]) * L2E);
                    _Float16 p3 = (_Float16)exp2f((e[3] - mreg[it]) * L2E);
                    if (jt == w)    // wave-uniform: each j counted exactly once globally
                        lrun[it] += (float)p0 + (float)p1 + (float)p2 + (float)p3;
                    union { _Float16 h[2]; uint32_t u; } u0, u1;
                    u0.h[0] = p0; u0.h[1] = p1;
                    u1.h[0] = p2; u1.h[1] = p3;
                    pk[jtl][it][0] = u0.u;
                    pk[jtl][it][1] = u1.u;
                }
                loadKs(s + 2, jtl);     // prefetch: same parity slot, 2 tiles ahead
            }
            // ---- PV for ksb: A-frag assembled in-register via bpermute ----
            __builtin_amdgcn_s_setprio(1);
#pragma unroll
            for (int it = 0; it < 4; ++it) {
                union { uint32_t wd[4]; f16x8 v; } af;
#pragma unroll
                for (int ww = 0; ww < 4; ++ww) {
                    const int idx = (ww < 2) ? idxA : idxB;
                    const int s0 = __builtin_amdgcn_ds_bpermute(idx, (int)pk[0][it][ww & 1]);
                    const int s1 = __builtin_amdgcn_ds_bpermute(idx, (int)pk[1][it][ww & 1]);
                    af.wd[ww] = (uint32_t)((g < 2) ? s0 : s1);
                }
#pragma unroll
                for (int ct = 0; ct < 4; ++ct)
                    acc[it][ct] = __builtin_amdgcn_mfma_f32_16x16x32_f16(af.v, vreg[ksb][ct], acc[it][ct], 0, 0, 0);
            }
            __builtin_amdgcn_s_setprio(0);
        }
    }

    // ---- reduce l across g and waves ----
#pragma unroll
    for (int it = 0; it < 4; ++it) {
        float s = lrun[it];
#pragma unroll
        for (int mask = 16; mask < 64; mask <<= 1)
            s += __shfl_xor(s, mask, 64);
        if (g == 0)
            lmw[w * 64 + it * 16 + lr] = s;
    }
    __syncthreads();
    if (tid < 64) {
        float ss = 0.f;
#pragma unroll
        for (int w2 = 0; w2 < 8; ++w2) ss += lmw[w2 * 64 + tid];
        lfin[tid] = ss;
    }
    __syncthreads();

    // ---- epilogue: out = gamma * acc / l + x (l from LDS) ----
    const float gm = gamma[0];
#pragma unroll
    for (int it = 0; it < 4; ++it) {
        const int rb = it * 16 + 4 * g;     // local row base for this lane's acc
        const int idx = ib + rb;
        float inv[4];
#pragma unroll
        for (int r = 0; r < 4; ++r)
            inv[r] = 1.0f / lfin[rb + r];
#pragma unroll
        for (int ct = 0; ct < 4; ++ct) {
            const int c = cw + ct * 16 + lr;
            const size_t base = (size_t)(b * CDIM + c) * NPOS + idx;
            const float4 xv = *reinterpret_cast<const float4*>(x + base);
            float4 ov;
            ov.x = gm * (acc[it][ct][0] * inv[0]) + xv.x;
            ov.y = gm * (acc[it][ct][1] * inv[1]) + xv.y;
            ov.z = gm * (acc[it][ct][2] * inv[2]) + xv.z;
            ov.w = gm * (acc[it][ct][3] * inv[3]) + xv.w;
            *reinterpret_cast<float4*>(out + base) = ov;
        }
    }
}

extern "C" void kernel_launch(void* const* d_in, const int* in_sizes, int n_in,
                              void* d_out, int out_size, void* d_ws, size_t ws_size,
                              hipStream_t stream)
{
    (void)in_sizes; (void)n_in; (void)out_size; (void)ws_size;

    const float* x     = (const float*)d_in[0];
    const float* wq    = (const float*)d_in[1];
    const float* bq    = (const float*)d_in[2];
    const float* wk    = (const float*)d_in[3];
    const float* bk    = (const float*)d_in[4];
    const float* wv    = (const float*)d_in[5];
    const float* bv    = (const float*)d_in[6];
    const float* gamma = (const float*)d_in[7];
    float* out = (float*)d_out;

    char* ws = (char*)d_ws;
    const size_t qkBytes = (size_t)NBATCH * NPOS * CQK * sizeof(_Float16);     //  2 MiB each
    const size_t vBytes  = (size_t)NBATCH * CDIM * NPOS * sizeof(_Float16);    // 16 MiB
    const size_t xtBytes = (size_t)NBATCH * NPOS * CDIM * sizeof(_Float16);    // 16 MiB

    _Float16* Qp = (_Float16*)(ws);
    _Float16* Kp = (_Float16*)(ws + qkBytes);
    _Float16* Vp = (_Float16*)(ws + 2 * qkBytes);
    _Float16* Xt = (_Float16*)(ws + 2 * qkBytes + vBytes);
    _Float16* Wh = (_Float16*)(ws + 2 * qkBytes + vBytes + xtBytes);
    float* biasc = (float*)(ws + 2 * qkBytes + vBytes + xtBytes
                              + (size_t)640 * CDIM * sizeof(_Float16));
    // total ws use ~= 36.6 MiB

    x_cvt_kernel<<<dim3(NPOS / 64, CDIM / 64, NBATCH), 256, 0, stream>>>(
        x, Xt, wq, bq, wk, bk, wv, bv, Wh, biasc);
    proj_gemm_kernel<<<dim3(NPOS / 128, 5, NBATCH), 256, 0, stream>>>(Wh, biasc, Xt, Qp, Kp, Vp);
    attn_fused_kernel<<<dim3(NPOS / 64 * NBATCH), 512, 0, stream>>>(x, Qp, Kp, Vp, gamma, out);
}

// Round 22
// 193.762 us; speedup vs baseline: 1.5989x; 1.5989x over previous
//
#include <hip/hip_runtime.h>
#include <hip/hip_fp16.h>

#define NPOS   4096
#define CDIM   512
#define CQK    64
#define NBATCH 4
#define L2E 1.44269504088896f

typedef _Float16 f16x8 __attribute__((ext_vector_type(8)));
typedef _Float16 f16x4 __attribute__((ext_vector_type(4)));
typedef float    f32x4 __attribute__((ext_vector_type(4)));

// LDS-only drain barrier: keeps global-load (vmcnt) prefetches in flight across
// the barrier (T4). All cross-wave traffic here is LDS, so lgkmcnt(0) suffices.
#define LDS_BARRIER() asm volatile("s_waitcnt lgkmcnt(0)\ns_barrier" ::: "memory")

// ---------------- x convert+transpose (+ fused weight convert) ----------------
// x[b,c,n] f32 -> Xt[b,n,c] f16 via padded LDS tile. Blocks with (z==0 && y==0)
// additionally convert concat[wq;wk;wv] -> Wh f16 and biases -> biasc.
__global__ __launch_bounds__(256) void x_cvt_kernel(
    const float* __restrict__ x, _Float16* __restrict__ Xt,
    const float* __restrict__ wq, const float* __restrict__ bq,
    const float* __restrict__ wk, const float* __restrict__ bk,
    const float* __restrict__ wv, const float* __restrict__ bv,
    _Float16* __restrict__ Wh, float* __restrict__ biasc)
{
    __shared__ _Float16 tile[64][66];
    const int b  = blockIdx.z;
    const int c0 = blockIdx.y * 64;
    const int n0 = blockIdx.x * 64;
    const int tid = threadIdx.x;

    if (blockIdx.z == 0 && blockIdx.y == 0) {
        const int gid = blockIdx.x * 256 + tid;          // 0..16383
#pragma unroll 1
        for (int idx4 = gid; idx4 < 640 * CDIM / 4; idx4 += 64 * 256) {
            const int idx = idx4 * 4;
            const float* src;
            if (idx < 64 * 512)       src = wq + idx;
            else if (idx < 128 * 512) src = wk + (idx - 64 * 512);
            else                      src = wv + (idx - 128 * 512);
            const float4 v = *reinterpret_cast<const float4*>(src);
            f16x4 h;
            h[0] = (_Float16)v.x; h[1] = (_Float16)v.y;
            h[2] = (_Float16)v.z; h[3] = (_Float16)v.w;
            *reinterpret_cast<f16x4*>(Wh + idx) = h;
        }
        if (gid < 640) {
            float bb;
            if (gid < 64)       bb = bq[gid];
            else if (gid < 128) bb = bk[gid - 64];
            else                bb = bv[gid - 128];
            biasc[gid] = bb;
        }
    }

    const int rr = tid >> 4;
    const int n4 = (tid & 15) * 4;
#pragma unroll
    for (int i = 0; i < 4; ++i) {
        const int c = i * 16 + rr;
        const float4 v = *reinterpret_cast<const float4*>(
            x + (size_t)(b * CDIM + c0 + c) * NPOS + n0 + n4);
        tile[c][n4 + 0] = (_Float16)v.x;
        tile[c][n4 + 1] = (_Float16)v.y;
        tile[c][n4 + 2] = (_Float16)v.z;
        tile[c][n4 + 3] = (_Float16)v.w;
    }
    __syncthreads();

    const int col = tid & 63;
    const int r4  = tid >> 6;
#pragma unroll
    for (int i = 0; i < 16; ++i) {
        const int n = i * 4 + r4;
        Xt[((size_t)b * NPOS + n0 + n) * CDIM + c0 + col] = tile[col][n];
    }
}

// ---------------- fused QKV projection GEMM: 128x128 tile, LDS double-buffered ----------------
// (R13 structure — measured best; unchanged.)
__global__ __launch_bounds__(256) void proj_gemm_kernel(
    const _Float16* __restrict__ Wh, const float* __restrict__ biasc,
    const _Float16* __restrict__ Xt,
    _Float16* __restrict__ Qp, _Float16* __restrict__ Kp, _Float16* __restrict__ Vp)
{
    __shared__ __align__(16) _Float16 As[2][128 * 32];
    __shared__ __align__(16) _Float16 Bs[2][128 * 32];

    const int tid  = threadIdx.x;
    const int lane = tid & 63;
    const int w    = tid >> 6;       // 0..3
    const int wr   = w >> 1;         // m-half
    const int wc   = w & 1;          // n-half
    const int g    = lane >> 4;
    const int lr   = lane & 15;

    const int b  = blockIdx.z;
    const int m0 = blockIdx.y * 128;
    const int n0 = blockIdx.x * 128;

    const _Float16* xb = Xt + (size_t)b * NPOS * CDIM;

    const int srow = tid >> 2;
    const int schk = (tid & 3) * 8;

    f16x8 sA[2], sB[2];
    auto gload = [&](int kk) {
#pragma unroll
        for (int rnd = 0; rnd < 2; ++rnd) {
            const int row = srow + rnd * 64;
            sA[rnd] = *reinterpret_cast<const f16x8*>(
                Wh + (size_t)(m0 + row) * CDIM + kk + schk);
            sB[rnd] = *reinterpret_cast<const f16x8*>(
                xb + (size_t)(n0 + row) * CDIM + kk + schk);
        }
    };
    auto dswrite = [&](int buf) {
#pragma unroll
        for (int rnd = 0; rnd < 2; ++rnd) {
            const int row = srow + rnd * 64;
            *reinterpret_cast<f16x8*>(&As[buf][row * 32 + schk]) = sA[rnd];
            *reinterpret_cast<f16x8*>(&Bs[buf][row * 32 + schk]) = sB[rnd];
        }
    };

    f32x4 acc[4][4];
#pragma unroll
    for (int it = 0; it < 4; ++it)
#pragma unroll
        for (int ct = 0; ct < 4; ++ct) {
            f32x4 z = {0.f, 0.f, 0.f, 0.f};
            acc[it][ct] = z;
        }

    auto compute = [&](int buf) {
        f16x8 a[4], bf[4];
#pragma unroll
        for (int it = 0; it < 4; ++it)
            a[it] = *reinterpret_cast<const f16x8*>(
                &As[buf][(wr * 64 + it * 16 + lr) * 32 + 8 * g]);
#pragma unroll
        for (int ct = 0; ct < 4; ++ct)
            bf[ct] = *reinterpret_cast<const f16x8*>(
                &Bs[buf][(wc * 64 + ct * 16 + lr) * 32 + 8 * g]);
#pragma unroll
        for (int it = 0; it < 4; ++it)
#pragma unroll
            for (int ct = 0; ct < 4; ++ct)
                acc[it][ct] = __builtin_amdgcn_mfma_f32_16x16x32_f16(a[it], bf[ct], acc[it][ct], 0, 0, 0);
    };

    gload(0);
    dswrite(0);
    __syncthreads();

#pragma unroll 1
    for (int t = 0; t < 16; ++t) {
        if (t < 15) gload((t + 1) * 32);
        compute(t & 1);
        if (t < 15) dswrite((t + 1) & 1);
        __syncthreads();
    }

    if (m0 == 0) {
        _Float16* dst = (wr == 0) ? Qp : Kp;
#pragma unroll
        for (int it = 0; it < 4; ++it) {
            const int gmb = m0 + wr * 64 + it * 16 + 4 * g;
            const int ob  = gmb & 63;
#pragma unroll
            for (int ct = 0; ct < 4; ++ct) {
                const int n = n0 + wc * 64 + ct * 16 + lr;
                f16x4 h;
#pragma unroll
                for (int r = 0; r < 4; ++r)
                    h[r] = (_Float16)(acc[it][ct][r] + biasc[gmb + r]);
                *reinterpret_cast<f16x4*>(dst + ((size_t)b * NPOS + n) * CQK + ob) = h;
            }
        }
    } else {
#pragma unroll
        for (int it = 0; it < 4; ++it) {
            const int gmb = m0 + wr * 64 + it * 16 + 4 * g;
#pragma unroll
            for (int ct = 0; ct < 4; ++ct) {
                const int n = n0 + wc * 64 + ct * 16 + lr;
#pragma unroll
                for (int r = 0; r < 4; ++r) {
                    const int c = gmb + r - 128;
                    Vp[((size_t)b * CDIM + c) * NPOS + n] =
                        (_Float16)(acc[it][ct][r] + biasc[gmb + r]);
                }
            }
        }
    }
}

// ---------------- Fused attention: pass 1 (row MAX only) + pass 2 (flash PV + l-from-P) ----------------
// (R18/R19/R20 structure — best measured configuration.)
__global__ __launch_bounds__(512, 2) void attn_fused_kernel(
    const float* __restrict__ x, const _Float16* __restrict__ Qp, const _Float16* __restrict__ Kp,
    const _Float16* __restrict__ Vp, const float* __restrict__ gamma, float* __restrict__ out)
{
    __shared__ __align__(16) _Float16 Pl[2][64 * 128];
    __shared__ float lmw[8 * 64];
    __shared__ float mfin[64];
    __shared__ float lfin[64];
    char* pb0 = (char*)Pl[0];
    char* pb1 = (char*)Pl[1];

    const int tid  = threadIdx.x;
    const int lane = tid & 63;
    const int w    = tid >> 6;      // 0..7
    const int g    = lane >> 4;     // 0..3
    const int lr   = lane & 15;

    // XCD-aware decode: batch b -> XCDs {2b,2b+1} so each XCD L2 holds one batch's V+K.
    const int bid = blockIdx.x;
    const int b   = (bid & 7) >> 1;
    const int ib  = (((bid >> 3) << 1) | (bid & 1)) * 64;
    const int cw  = w * 64;

    const _Float16* kb = Kp + (size_t)b * NPOS * CQK;
    const _Float16* vb = Vp + (size_t)b * CDIM * NPOS;

    f16x8 qf[4][2];
#pragma unroll
    for (int it = 0; it < 4; ++it)
#pragma unroll
        for (int ks = 0; ks < 2; ++ks)
            qf[it][ks] = *reinterpret_cast<const f16x8*>(
                Qp + (b * NPOS + ib + it * 16 + lr) * CQK + ks * 32 + 8 * g);

    f16x8 kA0, kA1, kB0, kB1;   // 2-slot K prefetch (pass 2)
    auto loadK = [&](int t, f16x8& k0, f16x8& k1) {
        const int tc = (t < 32) ? t : 31;
        const int j = tc * 128 + w * 16 + lr;
        k0 = *reinterpret_cast<const f16x8*>(kb + j * CQK + 8 * g);
        k1 = *reinterpret_cast<const f16x8*>(kb + j * CQK + 32 + 8 * g);
    };

    // ======== PASS 1: row max only (cheap VALU: 4 fmax-trees per chunk) ========
    {
        float mrun[4];
#pragma unroll
        for (int it = 0; it < 4; ++it) mrun[it] = -1e30f;

        auto step = [&](const f16x8& k0, const f16x8& k1) {
#pragma unroll
            for (int it = 0; it < 4; ++it) {
                f32x4 e = {0.f, 0.f, 0.f, 0.f};
                e = __builtin_amdgcn_mfma_f32_16x16x32_f16(k0, qf[it][0], e, 0, 0, 0);
                e = __builtin_amdgcn_mfma_f32_16x16x32_f16(k1, qf[it][1], e, 0, 0, 0);
                mrun[it] = fmaxf(mrun[it],
                                 fmaxf(fmaxf(e[0], e[1]), fmaxf(e[2], e[3])));
            }
        };

        loadK(0, kA0, kA1);
#pragma unroll 1
        for (int tp = 0; tp < 16; ++tp) {
            const int t = 2 * tp;
            loadK(t + 1, kB0, kB1);
            step(kA0, kA1);
            loadK(t + 2, kA0, kA1);
            step(kB0, kB1);
        }

        // reduce across g (lanes lr, lr+16, lr+32, lr+48), then across waves via LDS
#pragma unroll
        for (int it = 0; it < 4; ++it) {
            float m = mrun[it];
#pragma unroll
            for (int mask = 16; mask < 64; mask <<= 1)
                m = fmaxf(m, __shfl_xor(m, mask, 64));
            if (g == 0)
                lmw[w * 64 + it * 16 + lr] = m;
        }
        __syncthreads();

        if (tid < 64) {
            float mm = lmw[tid];
#pragma unroll
            for (int w2 = 1; w2 < 8; ++w2) mm = fmaxf(mm, lmw[w2 * 64 + tid]);
            mfin[tid] = mm;
        }
        __syncthreads();
    }

    // m for row i = ib + it*16 + lr
    float mreg[4];
#pragma unroll
    for (int it = 0; it < 4; ++it)
        mreg[it] = mfin[it * 16 + lr];

    // ======== PASS 2: flash PV (R16 schedule) + l accumulation from P ========
    f32x4 acc[4][4];
#pragma unroll
    for (int it = 0; it < 4; ++it)
#pragma unroll
        for (int ct = 0; ct < 4; ++ct) {
            f32x4 z = {0.f, 0.f, 0.f, 0.f};
            acc[it][ct] = z;
        }

    float lrun[4] = {0.f, 0.f, 0.f, 0.f};   // per-lane partial sums of P
    f16x8 vA[2][4], vB[2][4];   // half-chunk V buffers (ks 0-1 / ks 2-3), 32 VGPR each

    auto loadVh = [&](int t, int h, f16x8 (&vr)[2][4]) {
        const int tc = (t < 32) ? t : 31;
        const int jb = tc * 128;
#pragma unroll
        for (int ks2 = 0; ks2 < 2; ++ks2)
#pragma unroll
            for (int ct = 0; ct < 4; ++ct)
                vr[ks2][ct] = *reinterpret_cast<const f16x8*>(
                    vb + (size_t)(cw + ct * 16 + lr) * NPOS + jb + (2 * h + ks2) * 32 + 8 * g);
    };
    // E phase (SWAPPED): lane lr holds row i = it*16+lr, cols j = w*16+4g+{0..3}
    // -> one packed f16x4 LDS write per it. live=false for the tail-clamped duplicate
    // call (chunk index 32) so l isn't double-counted.
    auto ephase = [&](const f16x8& k0, const f16x8& k1, char* dst, bool live) {
#pragma unroll
        for (int it = 0; it < 4; ++it) {
            f32x4 e = {0.f, 0.f, 0.f, 0.f};
            e = __builtin_amdgcn_mfma_f32_16x16x32_f16(k0, qf[it][0], e, 0, 0, 0);
            e = __builtin_amdgcn_mfma_f32_16x16x32_f16(k1, qf[it][1], e, 0, 0, 0);
            f16x4 p;
#pragma unroll
            for (int r = 0; r < 4; ++r)
                p[r] = (_Float16)exp2f((e[r] - mreg[it]) * L2E);
            if (live)
                lrun[it] += (float)p[0] + (float)p[1] + (float)p[2] + (float)p[3];
            const int i   = it * 16 + lr;
            const int off = (i * 256 + (w * 32 + 8 * g)) ^ ((i & 15) << 4);
            *reinterpret_cast<f16x4*>(dst + off) = p;
        }
    };
    auto pvhalf = [&](const char* src, int h, const f16x8 (&vr)[2][4]) {
        __builtin_amdgcn_s_setprio(1);
#pragma unroll
        for (int ks2 = 0; ks2 < 2; ++ks2) {
            const int ks = 2 * h + ks2;
            f16x8 pa[4];
#pragma unroll
            for (int it = 0; it < 4; ++it) {
                const int off = (it * 16 + lr) * 256 + ((ks * 64 + g * 16) ^ (lr << 4));
                pa[it] = *reinterpret_cast<const f16x8*>(src + off);
            }
#pragma unroll
            for (int it = 0; it < 4; ++it)
#pragma unroll
                for (int ct = 0; ct < 4; ++ct)
                    acc[it][ct] = __builtin_amdgcn_mfma_f32_16x16x32_f16(pa[it], vr[ks2][ct], acc[it][ct], 0, 0, 0);
        }
        __builtin_amdgcn_s_setprio(0);
    };

    auto region = [&](int t, char* rbuf, char* wbuf, f16x8& ku0, f16x8& ku1,
                      f16x8& kl0, f16x8& kl1) {
        ephase(ku0, ku1, wbuf, (t + 1) < 32);   // P(t+1) using K(t+1)
        loadK(t + 2, kl0, kl1);                 // K(t+2) into the other slot
        pvhalf(rbuf, 0, vA);                    // PV(t) ks 0-1
        loadVh(t + 1, 0, vA);                   // V(t+1) ks 0-1
        pvhalf(rbuf, 1, vB);                    // PV(t) ks 2-3
        loadVh(t + 1, 1, vB);                   // V(t+1) ks 2-3
        LDS_BARRIER();
    };

    // Prologue: P(0) -> pb0, V(0) -> vA/vB, K(1) -> kA.
    loadK(0, kA0, kA1);
    loadVh(0, 0, vA);
    loadVh(0, 1, vB);
    ephase(kA0, kA1, pb0, true);        // P(0) (uses K(0) in kA)
    loadK(1, kA0, kA1);                 // K(1) -> kA (K(0) dead)
    __syncthreads();

#pragma unroll 1
    for (int tp = 0; tp < 16; ++tp) {
        const int t = 2 * tp;
        region(t,     pb0, pb1, kA0, kA1, kB0, kB1);   // chunk t:   P in pb0, K(t+1)=kA
        region(t + 1, pb1, pb0, kB0, kB1, kA0, kA1);   // chunk t+1: P in pb1, K(t+2)=kB
    }
    // (final region's ephase is live=false; all 32 chunks PV'd and l-counted once)

    // ---- reduce l across g and waves ----
#pragma unroll
    for (int it = 0; it < 4; ++it) {
        float s = lrun[it];
#pragma unroll
        for (int mask = 16; mask < 64; mask <<= 1)
            s += __shfl_xor(s, mask, 64);
        if (g == 0)
            lmw[w * 64 + it * 16 + lr] = s;
    }
    __syncthreads();
    if (tid < 64) {
        float ss = 0.f;
#pragma unroll
        for (int w2 = 0; w2 < 8; ++w2) ss += lmw[w2 * 64 + tid];
        lfin[tid] = ss;
    }
    __syncthreads();

    // ---- epilogue: out = gamma * acc / l + x (l from LDS) ----
    const float gm = gamma[0];
#pragma unroll
    for (int it = 0; it < 4; ++it) {
        const int rb = it * 16 + 4 * g;     // local row base for this lane's acc
        const int idx = ib + rb;
        float inv[4];
#pragma unroll
        for (int r = 0; r < 4; ++r)
            inv[r] = 1.0f / lfin[rb + r];
#pragma unroll
        for (int ct = 0; ct < 4; ++ct) {
            const int c = cw + ct * 16 + lr;
            const size_t base = (size_t)(b * CDIM + c) * NPOS + idx;
            const float4 xv = *reinterpret_cast<const float4*>(x + base);
            float4 ov;
            ov.x = gm * (acc[it][ct][0] * inv[0]) + xv.x;
            ov.y = gm * (acc[it][ct][1] * inv[1]) + xv.y;
            ov.z = gm * (acc[it][ct][2] * inv[2]) + xv.z;
            ov.w = gm * (acc[it][ct][3] * inv[3]) + xv.w;
            *reinterpret_cast<float4*>(out + base) = ov;
        }
    }
}

extern "C" void kernel_launch(void* const* d_in, const int* in_sizes, int n_in,
                              void* d_out, int out_size, void* d_ws, size_t ws_size,
                              hipStream_t stream)
{
    (void)in_sizes; (void)n_in; (void)out_size; (void)ws_size;

    const float* x     = (const float*)d_in[0];
    const float* wq    = (const float*)d_in[1];
    const float* bq    = (const float*)d_in[2];
    const float* wk    = (const float*)d_in[3];
    const float* bk    = (const float*)d_in[4];
    const float* wv    = (const float*)d_in[5];
    const float* bv    = (const float*)d_in[6];
    const float* gamma = (const float*)d_in[7];
    float* out = (float*)d_out;

    char* ws = (char*)d_ws;
    const size_t qkBytes = (size_t)NBATCH * NPOS * CQK * sizeof(_Float16);     //  2 MiB each
    const size_t vBytes  = (size_t)NBATCH * CDIM * NPOS * sizeof(_Float16);    // 16 MiB
    const size_t xtBytes = (size_t)NBATCH * NPOS * CDIM * sizeof(_Float16);    // 16 MiB

    _Float16* Qp = (_Float16*)(ws);
    _Float16* Kp = (_Float16*)(ws + qkBytes);
    _Float16* Vp = (_Float16*)(ws + 2 * qkBytes);
    _Float16* Xt = (_Float16*)(ws + 2 * qkBytes + vBytes);
    _Float16* Wh = (_Float16*)(ws + 2 * qkBytes + vBytes + xtBytes);
    float* biasc = (float*)(ws + 2 * qkBytes + vBytes + xtBytes
                              + (size_t)640 * CDIM * sizeof(_Float16));
    // total ws use ~= 36.6 MiB

    x_cvt_kernel<<<dim3(NPOS / 64, CDIM / 64, NBATCH), 256, 0, stream>>>(
        x, Xt, wq, bq, wk, bk, wv, bv, Wh, biasc);
    proj_gemm_kernel<<<dim3(NPOS / 128, 5, NBATCH), 256, 0, stream>>>(Wh, biasc, Xt, Qp, Kp, Vp);
    attn_fused_kernel<<<dim3(NPOS / 64 * NBATCH), 512, 0, stream>>>(x, Qp, Kp, Vp, gamma, out);
}

// Round 23
// 133.711 us; speedup vs baseline: 2.3170x; 1.4491x over previous
//
#include <hip/hip_runtime.h>
#include <hip/hip_fp16.h>

#define NPOS   4096
#define CDIM   512
#define CQK    64
#define NBATCH 4
#define L2E 1.44269504088896f

typedef _Float16 f16x8 __attribute__((ext_vector_type(8)));
typedef _Float16 f16x4 __attribute__((ext_vector_type(4)));
typedef float    f32x4 __attribute__((ext_vector_type(4)));

// LDS-only drain barrier: keeps global-load (vmcnt) prefetches in flight across
// the barrier (T4). All cross-wave traffic here is LDS, so lgkmcnt(0) suffices.
#define LDS_BARRIER() asm volatile("s_waitcnt lgkmcnt(0)\ns_barrier" ::: "memory")

// ---------------- x convert+transpose (+ fused weight convert) ----------------
// (R20 structure — measured best; unchanged.)
__global__ __launch_bounds__(256) void x_cvt_kernel(
    const float* __restrict__ x, _Float16* __restrict__ Xt,
    const float* __restrict__ wq, const float* __restrict__ bq,
    const float* __restrict__ wk, const float* __restrict__ bk,
    const float* __restrict__ wv, const float* __restrict__ bv,
    _Float16* __restrict__ Wh, float* __restrict__ biasc)
{
    __shared__ _Float16 tile[64][66];
    const int b  = blockIdx.z;
    const int c0 = blockIdx.y * 64;
    const int n0 = blockIdx.x * 64;
    const int tid = threadIdx.x;

    if (blockIdx.z == 0 && blockIdx.y == 0) {
        const int gid = blockIdx.x * 256 + tid;          // 0..16383
#pragma unroll 1
        for (int idx4 = gid; idx4 < 640 * CDIM / 4; idx4 += 64 * 256) {
            const int idx = idx4 * 4;
            const float* src;
            if (idx < 64 * 512)       src = wq + idx;
            else if (idx < 128 * 512) src = wk + (idx - 64 * 512);
            else                      src = wv + (idx - 128 * 512);
            const float4 v = *reinterpret_cast<const float4*>(src);
            f16x4 h;
            h[0] = (_Float16)v.x; h[1] = (_Float16)v.y;
            h[2] = (_Float16)v.z; h[3] = (_Float16)v.w;
            *reinterpret_cast<f16x4*>(Wh + idx) = h;
        }
        if (gid < 640) {
            float bb;
            if (gid < 64)       bb = bq[gid];
            else if (gid < 128) bb = bk[gid - 64];
            else                bb = bv[gid - 128];
            biasc[gid] = bb;
        }
    }

    const int rr = tid >> 4;
    const int n4 = (tid & 15) * 4;
#pragma unroll
    for (int i = 0; i < 4; ++i) {
        const int c = i * 16 + rr;
        const float4 v = *reinterpret_cast<const float4*>(
            x + (size_t)(b * CDIM + c0 + c) * NPOS + n0 + n4);
        tile[c][n4 + 0] = (_Float16)v.x;
        tile[c][n4 + 1] = (_Float16)v.y;
        tile[c][n4 + 2] = (_Float16)v.z;
        tile[c][n4 + 3] = (_Float16)v.w;
    }
    __syncthreads();

    const int col = tid & 63;
    const int r4  = tid >> 6;
#pragma unroll
    for (int i = 0; i < 16; ++i) {
        const int n = i * 4 + r4;
        Xt[((size_t)b * NPOS + n0 + n) * CDIM + c0 + col] = tile[col][n];
    }
}

// ---------------- fused QKV projection GEMM: 128x128 tile, LDS double-buffered ----------------
// R13 GEMM core unchanged. V epilogue now writes the FRAG-ORDERED V layout:
// Vp[b][cb=c/64][t=j/128][ks=(j/32)&3][ct_a=(c/16)&3][lane=4*((j/8)&3)... ]:
// flat idx = ((((((b*8+cb)*32+t)*4+ks)*4+ct_a)*4+ga)*16+lra)*8 + e, where for the
// proj-side value at (c = m0-128+wr*64+it*16+4g+r, j = n0+wc*64+ct*16+lr):
//   cb=((m0-128)>>6)+wr, t=n0>>7, ks=wc*2+(ct>>1), ct_a=it,
//   ga=(ct*2+(lr>>3))&3, lra=4g+r, e=lr&7.
// Pure relayout (same values, same rounding) -> attention math bitwise identical.
__global__ __launch_bounds__(256) void proj_gemm_kernel(
    const _Float16* __restrict__ Wh, const float* __restrict__ biasc,
    const _Float16* __restrict__ Xt,
    _Float16* __restrict__ Qp, _Float16* __restrict__ Kp, _Float16* __restrict__ Vp)
{
    __shared__ __align__(16) _Float16 As[2][128 * 32];
    __shared__ __align__(16) _Float16 Bs[2][128 * 32];

    const int tid  = threadIdx.x;
    const int lane = tid & 63;
    const int w    = tid >> 6;       // 0..3
    const int wr   = w >> 1;         // m-half
    const int wc   = w & 1;          // n-half
    const int g    = lane >> 4;
    const int lr   = lane & 15;

    const int b  = blockIdx.z;
    const int m0 = blockIdx.y * 128;
    const int n0 = blockIdx.x * 128;

    const _Float16* xb = Xt + (size_t)b * NPOS * CDIM;

    const int srow = tid >> 2;
    const int schk = (tid & 3) * 8;

    f16x8 sA[2], sB[2];
    auto gload = [&](int kk) {
#pragma unroll
        for (int rnd = 0; rnd < 2; ++rnd) {
            const int row = srow + rnd * 64;
            sA[rnd] = *reinterpret_cast<const f16x8*>(
                Wh + (size_t)(m0 + row) * CDIM + kk + schk);
            sB[rnd] = *reinterpret_cast<const f16x8*>(
                xb + (size_t)(n0 + row) * CDIM + kk + schk);
        }
    };
    auto dswrite = [&](int buf) {
#pragma unroll
        for (int rnd = 0; rnd < 2; ++rnd) {
            const int row = srow + rnd * 64;
            *reinterpret_cast<f16x8*>(&As[buf][row * 32 + schk]) = sA[rnd];
            *reinterpret_cast<f16x8*>(&Bs[buf][row * 32 + schk]) = sB[rnd];
        }
    };

    f32x4 acc[4][4];
#pragma unroll
    for (int it = 0; it < 4; ++it)
#pragma unroll
        for (int ct = 0; ct < 4; ++ct) {
            f32x4 z = {0.f, 0.f, 0.f, 0.f};
            acc[it][ct] = z;
        }

    auto compute = [&](int buf) {
        f16x8 a[4], bf[4];
#pragma unroll
        for (int it = 0; it < 4; ++it)
            a[it] = *reinterpret_cast<const f16x8*>(
                &As[buf][(wr * 64 + it * 16 + lr) * 32 + 8 * g]);
#pragma unroll
        for (int ct = 0; ct < 4; ++ct)
            bf[ct] = *reinterpret_cast<const f16x8*>(
                &Bs[buf][(wc * 64 + ct * 16 + lr) * 32 + 8 * g]);
#pragma unroll
        for (int it = 0; it < 4; ++it)
#pragma unroll
            for (int ct = 0; ct < 4; ++ct)
                acc[it][ct] = __builtin_amdgcn_mfma_f32_16x16x32_f16(a[it], bf[ct], acc[it][ct], 0, 0, 0);
    };

    gload(0);
    dswrite(0);
    __syncthreads();

#pragma unroll 1
    for (int t = 0; t < 16; ++t) {
        if (t < 15) gload((t + 1) * 32);
        compute(t & 1);
        if (t < 15) dswrite((t + 1) & 1);
        __syncthreads();
    }

    if (m0 == 0) {
        _Float16* dst = (wr == 0) ? Qp : Kp;
#pragma unroll
        for (int it = 0; it < 4; ++it) {
            const int gmb = m0 + wr * 64 + it * 16 + 4 * g;
            const int ob  = gmb & 63;
#pragma unroll
            for (int ct = 0; ct < 4; ++ct) {
                const int n = n0 + wc * 64 + ct * 16 + lr;
                f16x4 h;
#pragma unroll
                for (int r = 0; r < 4; ++r)
                    h[r] = (_Float16)(acc[it][ct][r] + biasc[gmb + r]);
                *reinterpret_cast<f16x4*>(dst + ((size_t)b * NPOS + n) * CQK + ob) = h;
            }
        }
    } else {
        const int cb = ((m0 - 128) >> 6) + wr;
        const int t  = n0 >> 7;
#pragma unroll
        for (int it = 0; it < 4; ++it) {
            const int gmb = m0 + wr * 64 + it * 16 + 4 * g;
#pragma unroll
            for (int ct = 0; ct < 4; ++ct) {
                const int ks = wc * 2 + (ct >> 1);
                const int ga = (ct * 2 + (lr >> 3)) & 3;
                const int e  = lr & 7;
#pragma unroll
                for (int r = 0; r < 4; ++r) {
                    const int lra = 4 * g + r;
                    const size_t idx =
                        ((((((size_t)b * 8 + cb) * 32 + t) * 4 + ks) * 4 + it) * 4 + ga) * 16 + lra;
                    Vp[idx * 8 + e] = (_Float16)(acc[it][ct][r] + biasc[gmb + r]);
                }
            }
        }
    }
}

// ---------------- Fused attention: pass 1 (row MAX only) + pass 2 (flash PV + l-from-P) ----------------
// R18/R20 structure; ONLY change: V is read from the frag-ordered layout, so each
// loadVh frag is per-wave-uniform-base + lane*16B -> one fully-coalesced 1KB request
// per instruction (previously 64 distinct cache lines per instruction, TA-serialized
// issue cost that no prefetch/occupancy/barrier lever could hide).
__global__ __launch_bounds__(512, 2) void attn_fused_kernel(
    const float* __restrict__ x, const _Float16* __restrict__ Qp, const _Float16* __restrict__ Kp,
    const _Float16* __restrict__ Vp, const float* __restrict__ gamma, float* __restrict__ out)
{
    __shared__ __align__(16) _Float16 Pl[2][64 * 128];
    __shared__ float lmw[8 * 64];
    __shared__ float mfin[64];
    __shared__ float lfin[64];
    char* pb0 = (char*)Pl[0];
    char* pb1 = (char*)Pl[1];

    const int tid  = threadIdx.x;
    const int lane = tid & 63;
    const int w    = tid >> 6;      // 0..7
    const int g    = lane >> 4;     // 0..3
    const int lr   = lane & 15;

    // XCD-aware decode: batch b -> XCDs {2b,2b+1} so each XCD L2 holds one batch's V+K.
    const int bid = blockIdx.x;
    const int b   = (bid & 7) >> 1;
    const int ib  = (((bid >> 3) << 1) | (bid & 1)) * 64;
    const int cw  = w * 64;

    const _Float16* kb  = Kp + (size_t)b * NPOS * CQK;
    // frag-ordered V: per-(b, cb=w) block of 32t*4ks*4ct*64lane*8 = 262144 f16
    const _Float16* vbw = Vp + ((size_t)b * 8 + w) * 262144;

    f16x8 qf[4][2];
#pragma unroll
    for (int it = 0; it < 4; ++it)
#pragma unroll
        for (int ks = 0; ks < 2; ++ks)
            qf[it][ks] = *reinterpret_cast<const f16x8*>(
                Qp + (b * NPOS + ib + it * 16 + lr) * CQK + ks * 32 + 8 * g);

    f16x8 kA0, kA1, kB0, kB1;   // 2-slot K prefetch (pass 2)
    auto loadK = [&](int t, f16x8& k0, f16x8& k1) {
        const int tc = (t < 32) ? t : 31;
        const int j = tc * 128 + w * 16 + lr;
        k0 = *reinterpret_cast<const f16x8*>(kb + j * CQK + 8 * g);
        k1 = *reinterpret_cast<const f16x8*>(kb + j * CQK + 32 + 8 * g);
    };

    // ======== PASS 1: row max only (cheap VALU: 4 fmax-trees per chunk) ========
    {
        float mrun[4];
#pragma unroll
        for (int it = 0; it < 4; ++it) mrun[it] = -1e30f;

        auto step = [&](const f16x8& k0, const f16x8& k1) {
#pragma unroll
            for (int it = 0; it < 4; ++it) {
                f32x4 e = {0.f, 0.f, 0.f, 0.f};
                e = __builtin_amdgcn_mfma_f32_16x16x32_f16(k0, qf[it][0], e, 0, 0, 0);
                e = __builtin_amdgcn_mfma_f32_16x16x32_f16(k1, qf[it][1], e, 0, 0, 0);
                mrun[it] = fmaxf(mrun[it],
                                 fmaxf(fmaxf(e[0], e[1]), fmaxf(e[2], e[3])));
            }
        };

        loadK(0, kA0, kA1);
#pragma unroll 1
        for (int tp = 0; tp < 16; ++tp) {
            const int t = 2 * tp;
            loadK(t + 1, kB0, kB1);
            step(kA0, kA1);
            loadK(t + 2, kA0, kA1);
            step(kB0, kB1);
        }

        // reduce across g (lanes lr, lr+16, lr+32, lr+48), then across waves via LDS
#pragma unroll
        for (int it = 0; it < 4; ++it) {
            float m = mrun[it];
#pragma unroll
            for (int mask = 16; mask < 64; mask <<= 1)
                m = fmaxf(m, __shfl_xor(m, mask, 64));
            if (g == 0)
                lmw[w * 64 + it * 16 + lr] = m;
        }
        __syncthreads();

        if (tid < 64) {
            float mm = lmw[tid];
#pragma unroll
            for (int w2 = 1; w2 < 8; ++w2) mm = fmaxf(mm, lmw[w2 * 64 + tid]);
            mfin[tid] = mm;
        }
        __syncthreads();
    }

    // m for row i = ib + it*16 + lr
    float mreg[4];
#pragma unroll
    for (int it = 0; it < 4; ++it)
        mreg[it] = mfin[it * 16 + lr];

    // ======== PASS 2: flash PV (R16 schedule) + l accumulation from P ========
    f32x4 acc[4][4];
#pragma unroll
    for (int it = 0; it < 4; ++it)
#pragma unroll
        for (int ct = 0; ct < 4; ++ct) {
            f32x4 z = {0.f, 0.f, 0.f, 0.f};
            acc[it][ct] = z;
        }

    float lrun[4] = {0.f, 0.f, 0.f, 0.f};   // per-lane partial sums of P
    f16x8 vA[2][4], vB[2][4];   // half-chunk V buffers (ks 0-1 / ks 2-3), 32 VGPR each

    // frag-ordered V read: fully coalesced (uniform base + lane*16B)
    auto loadVh = [&](int t, int h, f16x8 (&vr)[2][4]) {
        const int tc = (t < 32) ? t : 31;
        const _Float16* base = vbw + (size_t)tc * 8192 + lane * 8;
#pragma unroll
        for (int ks2 = 0; ks2 < 2; ++ks2)
#pragma unroll
            for (int ct = 0; ct < 4; ++ct)
                vr[ks2][ct] = *reinterpret_cast<const f16x8*>(
                    base + (2 * h + ks2) * 2048 + ct * 512);
    };
    // E phase (SWAPPED): lane lr holds row i = it*16+lr, cols j = w*16+4g+{0..3}
    // -> one packed f16x4 LDS write per it. live=false for the tail-clamped duplicate
    // call (chunk index 32) so l isn't double-counted.
    auto ephase = [&](const f16x8& k0, const f16x8& k1, char* dst, bool live) {
#pragma unroll
        for (int it = 0; it < 4; ++it) {
            f32x4 e = {0.f, 0.f, 0.f, 0.f};
            e = __builtin_amdgcn_mfma_f32_16x16x32_f16(k0, qf[it][0], e, 0, 0, 0);
            e = __builtin_amdgcn_mfma_f32_16x16x32_f16(k1, qf[it][1], e, 0, 0, 0);
            f16x4 p;
#pragma unroll
            for (int r = 0; r < 4; ++r)
                p[r] = (_Float16)exp2f((e[r] - mreg[it]) * L2E);
            if (live)
                lrun[it] += (float)p[0] + (float)p[1] + (float)p[2] + (float)p[3];
            const int i   = it * 16 + lr;
            const int off = (i * 256 + (w * 32 + 8 * g)) ^ ((i & 15) << 4);
            *reinterpret_cast<f16x4*>(dst + off) = p;
        }
    };
    auto pvhalf = [&](const char* src, int h, const f16x8 (&vr)[2][4]) {
        __builtin_amdgcn_s_setprio(1);
#pragma unroll
        for (int ks2 = 0; ks2 < 2; ++ks2) {
            const int ks = 2 * h + ks2;
            f16x8 pa[4];
#pragma unroll
            for (int it = 0; it < 4; ++it) {
                const int off = (it * 16 + lr) * 256 + ((ks * 64 + g * 16) ^ (lr << 4));
                pa[it] = *reinterpret_cast<const f16x8*>(src + off);
            }
#pragma unroll
            for (int it = 0; it < 4; ++it)
#pragma unroll
                for (int ct = 0; ct < 4; ++ct)
                    acc[it][ct] = __builtin_amdgcn_mfma_f32_16x16x32_f16(pa[it], vr[ks2][ct], acc[it][ct], 0, 0, 0);
        }
        __builtin_amdgcn_s_setprio(0);
    };

    auto region = [&](int t, char* rbuf, char* wbuf, f16x8& ku0, f16x8& ku1,
                      f16x8& kl0, f16x8& kl1) {
        ephase(ku0, ku1, wbuf, (t + 1) < 32);   // P(t+1) using K(t+1)
        loadK(t + 2, kl0, kl1);                 // K(t+2) into the other slot
        pvhalf(rbuf, 0, vA);                    // PV(t) ks 0-1
        loadVh(t + 1, 0, vA);                   // V(t+1) ks 0-1
        pvhalf(rbuf, 1, vB);                    // PV(t) ks 2-3
        loadVh(t + 1, 1, vB);                   // V(t+1) ks 2-3
        LDS_BARRIER();
    };

    // Prologue: P(0) -> pb0, V(0) -> vA/vB, K(1) -> kA.
    loadK(0, kA0, kA1);
    loadVh(0, 0, vA);
    loadVh(0, 1, vB);
    ephase(kA0, kA1, pb0, true);        // P(0) (uses K(0) in kA)
    loadK(1, kA0, kA1);                 // K(1) -> kA (K(0) dead)
    __syncthreads();

#pragma unroll 1
    for (int tp = 0; tp < 16; ++tp) {
        const int t = 2 * tp;
        region(t,     pb0, pb1, kA0, kA1, kB0, kB1);   // chunk t:   P in pb0, K(t+1)=kA
        region(t + 1, pb1, pb0, kB0, kB1, kA0, kA1);   // chunk t+1: P in pb1, K(t+2)=kB
    }
    // (final region's ephase is live=false; all 32 chunks PV'd and l-counted once)

    // ---- reduce l across g and waves ----
#pragma unroll
    for (int it = 0; it < 4; ++it) {
        float s = lrun[it];
#pragma unroll
        for (int mask = 16; mask < 64; mask <<= 1)
            s += __shfl_xor(s, mask, 64);
        if (g == 0)
            lmw[w * 64 + it * 16 + lr] = s;
    }
    __syncthreads();
    if (tid < 64) {
        float ss = 0.f;
#pragma unroll
        for (int w2 = 0; w2 < 8; ++w2) ss += lmw[w2 * 64 + tid];
        lfin[tid] = ss;
    }
    __syncthreads();

    // ---- epilogue: out = gamma * acc / l + x (l from LDS) ----
    const float gm = gamma[0];
#pragma unroll
    for (int it = 0; it < 4; ++it) {
        const int rb = it * 16 + 4 * g;     // local row base for this lane's acc
        const int idx = ib + rb;
        float inv[4];
#pragma unroll
        for (int r = 0; r < 4; ++r)
            inv[r] = 1.0f / lfin[rb + r];
#pragma unroll
        for (int ct = 0; ct < 4; ++ct) {
            const int c = cw + ct * 16 + lr;
            const size_t base = (size_t)(b * CDIM + c) * NPOS + idx;
            const float4 xv = *reinterpret_cast<const float4*>(x + base);
            float4 ov;
            ov.x = gm * (acc[it][ct][0] * inv[0]) + xv.x;
            ov.y = gm * (acc[it][ct][1] * inv[1]) + xv.y;
            ov.z = gm * (acc[it][ct][2] * inv[2]) + xv.z;
            ov.w = gm * (acc[it][ct][3] * inv[3]) + xv.w;
            *reinterpret_cast<float4*>(out + base) = ov;
        }
    }
}

extern "C" void kernel_launch(void* const* d_in, const int* in_sizes, int n_in,
                              void* d_out, int out_size, void* d_ws, size_t ws_size,
                              hipStream_t stream)
{
    (void)in_sizes; (void)n_in; (void)out_size; (void)ws_size;

    const float* x     = (const float*)d_in[0];
    const float* wq    = (const float*)d_in[1];
    const float* bq    = (const float*)d_in[2];
    const float* wk    = (const float*)d_in[3];
    const float* bk    = (const float*)d_in[4];
    const float* wv    = (const float*)d_in[5];
    const float* bv    = (const float*)d_in[6];
    const float* gamma = (const float*)d_in[7];
    float* out = (float*)d_out;

    char* ws = (char*)d_ws;
    const size_t qkBytes = (size_t)NBATCH * NPOS * CQK * sizeof(_Float16);     //  2 MiB each
    const size_t vBytes  = (size_t)NBATCH * CDIM * NPOS * sizeof(_Float16);    // 16 MiB (frag-ordered)
    const size_t xtBytes = (size_t)NBATCH * NPOS * CDIM * sizeof(_Float16);    // 16 MiB

    _Float16* Qp = (_Float16*)(ws);
    _Float16* Kp = (_Float16*)(ws + qkBytes);
    _Float16* Vp = (_Float16*)(ws + 2 * qkBytes);
    _Float16* Xt = (_Float16*)(ws + 2 * qkBytes + vBytes);
    _Float16* Wh = (_Float16*)(ws + 2 * qkBytes + vBytes + xtBytes);
    float* biasc = (float*)(ws + 2 * qkBytes + vBytes + xtBytes
                              + (size_t)640 * CDIM * sizeof(_Float16));
    // total ws use ~= 36.6 MiB

    x_cvt_kernel<<<dim3(NPOS / 64, CDIM / 64, NBATCH), 256, 0, stream>>>(
        x, Xt, wq, bq, wk, bk, wv, bv, Wh, biasc);
    proj_gemm_kernel<<<dim3(NPOS / 128, 5, NBATCH), 256, 0, stream>>>(Wh, biasc, Xt, Qp, Kp, Vp);
    attn_fused_kernel<<<dim3(NPOS / 64 * NBATCH), 512, 0, stream>>>(x, Qp, Kp, Vp, gamma, out);
}

// Round 24
// 128.096 us; speedup vs baseline: 2.4185x; 1.0438x over previous
//
#include <hip/hip_runtime.h>
#include <hip/hip_fp16.h>

#define NPOS   4096
#define CDIM   512
#define CQK    64
#define NBATCH 4
#define L2E 1.44269504088896f

typedef _Float16 f16x8 __attribute__((ext_vector_type(8)));
typedef _Float16 f16x4 __attribute__((ext_vector_type(4)));
typedef float    f32x4 __attribute__((ext_vector_type(4)));

// LDS-only drain barrier: keeps global-load (vmcnt) prefetches in flight across
// the barrier (T4). All cross-wave traffic here is LDS, so lgkmcnt(0) suffices.
#define LDS_BARRIER() asm volatile("s_waitcnt lgkmcnt(0)\ns_barrier" ::: "memory")

// ---------------- x convert+transpose (+ fused weight convert) ----------------
// (R20 structure — measured best; unchanged.)
__global__ __launch_bounds__(256) void x_cvt_kernel(
    const float* __restrict__ x, _Float16* __restrict__ Xt,
    const float* __restrict__ wq, const float* __restrict__ bq,
    const float* __restrict__ wk, const float* __restrict__ bk,
    const float* __restrict__ wv, const float* __restrict__ bv,
    _Float16* __restrict__ Wh, float* __restrict__ biasc)
{
    __shared__ _Float16 tile[64][66];
    const int b  = blockIdx.z;
    const int c0 = blockIdx.y * 64;
    const int n0 = blockIdx.x * 64;
    const int tid = threadIdx.x;

    if (blockIdx.z == 0 && blockIdx.y == 0) {
        const int gid = blockIdx.x * 256 + tid;          // 0..16383
#pragma unroll 1
        for (int idx4 = gid; idx4 < 640 * CDIM / 4; idx4 += 64 * 256) {
            const int idx = idx4 * 4;
            const float* src;
            if (idx < 64 * 512)       src = wq + idx;
            else if (idx < 128 * 512) src = wk + (idx - 64 * 512);
            else                      src = wv + (idx - 128 * 512);
            const float4 v = *reinterpret_cast<const float4*>(src);
            f16x4 h;
            h[0] = (_Float16)v.x; h[1] = (_Float16)v.y;
            h[2] = (_Float16)v.z; h[3] = (_Float16)v.w;
            *reinterpret_cast<f16x4*>(Wh + idx) = h;
        }
        if (gid < 640) {
            float bb;
            if (gid < 64)       bb = bq[gid];
            else if (gid < 128) bb = bk[gid - 64];
            else                bb = bv[gid - 128];
            biasc[gid] = bb;
        }
    }

    const int rr = tid >> 4;
    const int n4 = (tid & 15) * 4;
#pragma unroll
    for (int i = 0; i < 4; ++i) {
        const int c = i * 16 + rr;
        const float4 v = *reinterpret_cast<const float4*>(
            x + (size_t)(b * CDIM + c0 + c) * NPOS + n0 + n4);
        tile[c][n4 + 0] = (_Float16)v.x;
        tile[c][n4 + 1] = (_Float16)v.y;
        tile[c][n4 + 2] = (_Float16)v.z;
        tile[c][n4 + 3] = (_Float16)v.w;
    }
    __syncthreads();

    const int col = tid & 63;
    const int r4  = tid >> 6;
#pragma unroll
    for (int i = 0; i < 16; ++i) {
        const int n = i * 4 + r4;
        Xt[((size_t)b * NPOS + n0 + n) * CDIM + c0 + col] = tile[col][n];
    }
}

// ---------------- fused QKV projection GEMM: 128x128 tile, LDS double-buffered ----------------
// R13 GEMM core unchanged. Epilogues write FRAG-ORDERED K and V:
//  K: Kf[b][s=j/16][chunk=o/32][lane'=((o%32)/8)*16 + j%16][e=o%8]
//     (attention reads chunk frags as uniform-base + lane*16B -> coalesced 1KB)
//  V: Vp[b][cb=c/64][t=j/128][ks=(j/32)&3][ct_a=(c/16)&3][ga][lra][e]  (R23 layout)
// Pure relayout (same values, same rounding) -> attention math bitwise identical.
__global__ __launch_bounds__(256) void proj_gemm_kernel(
    const _Float16* __restrict__ Wh, const float* __restrict__ biasc,
    const _Float16* __restrict__ Xt,
    _Float16* __restrict__ Qp, _Float16* __restrict__ Kp, _Float16* __restrict__ Vp)
{
    __shared__ __align__(16) _Float16 As[2][128 * 32];
    __shared__ __align__(16) _Float16 Bs[2][128 * 32];

    const int tid  = threadIdx.x;
    const int lane = tid & 63;
    const int w    = tid >> 6;       // 0..3
    const int wr   = w >> 1;         // m-half
    const int wc   = w & 1;          // n-half
    const int g    = lane >> 4;
    const int lr   = lane & 15;

    const int b  = blockIdx.z;
    const int m0 = blockIdx.y * 128;
    const int n0 = blockIdx.x * 128;

    const _Float16* xb = Xt + (size_t)b * NPOS * CDIM;

    const int srow = tid >> 2;
    const int schk = (tid & 3) * 8;

    f16x8 sA[2], sB[2];
    auto gload = [&](int kk) {
#pragma unroll
        for (int rnd = 0; rnd < 2; ++rnd) {
            const int row = srow + rnd * 64;
            sA[rnd] = *reinterpret_cast<const f16x8*>(
                Wh + (size_t)(m0 + row) * CDIM + kk + schk);
            sB[rnd] = *reinterpret_cast<const f16x8*>(
                xb + (size_t)(n0 + row) * CDIM + kk + schk);
        }
    };
    auto dswrite = [&](int buf) {
#pragma unroll
        for (int rnd = 0; rnd < 2; ++rnd) {
            const int row = srow + rnd * 64;
            *reinterpret_cast<f16x8*>(&As[buf][row * 32 + schk]) = sA[rnd];
            *reinterpret_cast<f16x8*>(&Bs[buf][row * 32 + schk]) = sB[rnd];
        }
    };

    f32x4 acc[4][4];
#pragma unroll
    for (int it = 0; it < 4; ++it)
#pragma unroll
        for (int ct = 0; ct < 4; ++ct) {
            f32x4 z = {0.f, 0.f, 0.f, 0.f};
            acc[it][ct] = z;
        }

    auto compute = [&](int buf) {
        f16x8 a[4], bf[4];
#pragma unroll
        for (int it = 0; it < 4; ++it)
            a[it] = *reinterpret_cast<const f16x8*>(
                &As[buf][(wr * 64 + it * 16 + lr) * 32 + 8 * g]);
#pragma unroll
        for (int ct = 0; ct < 4; ++ct)
            bf[ct] = *reinterpret_cast<const f16x8*>(
                &Bs[buf][(wc * 64 + ct * 16 + lr) * 32 + 8 * g]);
#pragma unroll
        for (int it = 0; it < 4; ++it)
#pragma unroll
            for (int ct = 0; ct < 4; ++ct)
                acc[it][ct] = __builtin_amdgcn_mfma_f32_16x16x32_f16(a[it], bf[ct], acc[it][ct], 0, 0, 0);
    };

    gload(0);
    dswrite(0);
    __syncthreads();

#pragma unroll 1
    for (int t = 0; t < 16; ++t) {
        if (t < 15) gload((t + 1) * 32);
        compute(t & 1);
        if (t < 15) dswrite((t + 1) & 1);
        __syncthreads();
    }

    if (m0 == 0) {
        if (wr == 0) {
            // Q rows 0..63 — layout unchanged ([n][o], consumed once per block)
#pragma unroll
            for (int it = 0; it < 4; ++it) {
                const int gmb = it * 16 + 4 * g;
#pragma unroll
                for (int ct = 0; ct < 4; ++ct) {
                    const int n = n0 + wc * 64 + ct * 16 + lr;
                    f16x4 h;
#pragma unroll
                    for (int r = 0; r < 4; ++r)
                        h[r] = (_Float16)(acc[it][ct][r] + biasc[gmb + r]);
                    *reinterpret_cast<f16x4*>(Qp + ((size_t)b * NPOS + n) * CQK + gmb) = h;
                }
            }
        } else {
            // K rows 64..127 — FRAG-ORDERED: Kf[b][s][chunk][lane'][e]
#pragma unroll
            for (int it = 0; it < 4; ++it) {
                const int o0    = it * 16 + 4 * g;      // o = o0 + r
                const int gmb   = 64 + o0;              // bias index
                const int chunk = o0 >> 5;
                const int gp    = (o0 & 31) >> 3;
                const int e0    = o0 & 7;               // 0 or 4
#pragma unroll
                for (int ct = 0; ct < 4; ++ct) {
                    const int n  = n0 + wc * 64 + ct * 16 + lr;
                    const int s  = n >> 4;
                    const int jl = n & 15;
                    f16x4 h;
#pragma unroll
                    for (int r = 0; r < 4; ++r)
                        h[r] = (_Float16)(acc[it][ct][r] + biasc[gmb + r]);
                    const size_t idx =
                        ((((size_t)b * 256 + s) * 2 + chunk) * 64 + gp * 16 + jl) * 8 + e0;
                    *reinterpret_cast<f16x4*>(Kp + idx) = h;
                }
            }
        }
    } else {
        const int cb = ((m0 - 128) >> 6) + wr;
        const int t  = n0 >> 7;
#pragma unroll
        for (int it = 0; it < 4; ++it) {
            const int gmb = m0 + wr * 64 + it * 16 + 4 * g;
#pragma unroll
            for (int ct = 0; ct < 4; ++ct) {
                const int ks = wc * 2 + (ct >> 1);
                const int ga = (ct * 2 + (lr >> 3)) & 3;
                const int e  = lr & 7;
#pragma unroll
                for (int r = 0; r < 4; ++r) {
                    const int lra = 4 * g + r;
                    const size_t idx =
                        ((((((size_t)b * 8 + cb) * 32 + t) * 4 + ks) * 4 + it) * 4 + ga) * 16 + lra;
                    Vp[idx * 8 + e] = (_Float16)(acc[it][ct][r] + biasc[gmb + r]);
                }
            }
        }
    }
}

// ---------------- Fused attention: pass 1 (row MAX only) + pass 2 (flash PV + l-from-P) ----------------
// R23 structure; K now also frag-ordered -> loadK is uniform-base + lane*16B
// (one coalesced 1KB request per chunk frag, was 16 distinct 128B lines).
__global__ __launch_bounds__(512, 2) void attn_fused_kernel(
    const float* __restrict__ x, const _Float16* __restrict__ Qp, const _Float16* __restrict__ Kp,
    const _Float16* __restrict__ Vp, const float* __restrict__ gamma, float* __restrict__ out)
{
    __shared__ __align__(16) _Float16 Pl[2][64 * 128];
    __shared__ float lmw[8 * 64];
    __shared__ float mfin[64];
    __shared__ float lfin[64];
    char* pb0 = (char*)Pl[0];
    char* pb1 = (char*)Pl[1];

    const int tid  = threadIdx.x;
    const int lane = tid & 63;
    const int w    = tid >> 6;      // 0..7
    const int g    = lane >> 4;     // 0..3
    const int lr   = lane & 15;

    // XCD-aware decode: batch b -> XCDs {2b,2b+1} so each XCD L2 holds one batch's V+K.
    const int bid = blockIdx.x;
    const int b   = (bid & 7) >> 1;
    const int ib  = (((bid >> 3) << 1) | (bid & 1)) * 64;
    const int cw  = w * 64;

    const _Float16* kb  = Kp + (size_t)b * 262144;           // frag-ordered K
    const _Float16* vbw = Vp + ((size_t)b * 8 + w) * 262144; // frag-ordered V (per-wave c-block)

    f16x8 qf[4][2];
#pragma unroll
    for (int it = 0; it < 4; ++it)
#pragma unroll
        for (int ks = 0; ks < 2; ++ks)
            qf[it][ks] = *reinterpret_cast<const f16x8*>(
                Qp + (b * NPOS + ib + it * 16 + lr) * CQK + ks * 32 + 8 * g);

    f16x8 kA0, kA1, kB0, kB1;   // 2-slot K prefetch (pass 2)
    // frag-ordered K read: fully coalesced (uniform base + lane*16B)
    auto loadK = [&](int t, f16x8& k0, f16x8& k1) {
        const int tc = (t < 32) ? t : 31;
        const _Float16* p = kb + ((size_t)(tc * 8 + w) * 2) * 512 + lane * 8;
        k0 = *reinterpret_cast<const f16x8*>(p);
        k1 = *reinterpret_cast<const f16x8*>(p + 512);
    };

    // ======== PASS 1: row max only (cheap VALU: 4 fmax-trees per chunk) ========
    {
        float mrun[4];
#pragma unroll
        for (int it = 0; it < 4; ++it) mrun[it] = -1e30f;

        auto step = [&](const f16x8& k0, const f16x8& k1) {
#pragma unroll
            for (int it = 0; it < 4; ++it) {
                f32x4 e = {0.f, 0.f, 0.f, 0.f};
                e = __builtin_amdgcn_mfma_f32_16x16x32_f16(k0, qf[it][0], e, 0, 0, 0);
                e = __builtin_amdgcn_mfma_f32_16x16x32_f16(k1, qf[it][1], e, 0, 0, 0);
                mrun[it] = fmaxf(mrun[it],
                                 fmaxf(fmaxf(e[0], e[1]), fmaxf(e[2], e[3])));
            }
        };

        loadK(0, kA0, kA1);
#pragma unroll 1
        for (int tp = 0; tp < 16; ++tp) {
            const int t = 2 * tp;
            loadK(t + 1, kB0, kB1);
            step(kA0, kA1);
            loadK(t + 2, kA0, kA1);
            step(kB0, kB1);
        }

        // reduce across g (lanes lr, lr+16, lr+32, lr+48), then across waves via LDS
#pragma unroll
        for (int it = 0; it < 4; ++it) {
            float m = mrun[it];
#pragma unroll
            for (int mask = 16; mask < 64; mask <<= 1)
                m = fmaxf(m, __shfl_xor(m, mask, 64));
            if (g == 0)
                lmw[w * 64 + it * 16 + lr] = m;
        }
        __syncthreads();

        if (tid < 64) {
            float mm = lmw[tid];
#pragma unroll
            for (int w2 = 1; w2 < 8; ++w2) mm = fmaxf(mm, lmw[w2 * 64 + tid]);
            mfin[tid] = mm;
        }
        __syncthreads();
    }

    // m for row i = ib + it*16 + lr
    float mreg[4];
#pragma unroll
    for (int it = 0; it < 4; ++it)
        mreg[it] = mfin[it * 16 + lr];

    // ======== PASS 2: flash PV (R16 schedule) + l accumulation from P ========
    f32x4 acc[4][4];
#pragma unroll
    for (int it = 0; it < 4; ++it)
#pragma unroll
        for (int ct = 0; ct < 4; ++ct) {
            f32x4 z = {0.f, 0.f, 0.f, 0.f};
            acc[it][ct] = z;
        }

    float lrun[4] = {0.f, 0.f, 0.f, 0.f};   // per-lane partial sums of P
    f16x8 vA[2][4], vB[2][4];   // half-chunk V buffers (ks 0-1 / ks 2-3), 32 VGPR each

    // frag-ordered V read: fully coalesced (uniform base + lane*16B)
    auto loadVh = [&](int t, int h, f16x8 (&vr)[2][4]) {
        const int tc = (t < 32) ? t : 31;
        const _Float16* base = vbw + (size_t)tc * 8192 + lane * 8;
#pragma unroll
        for (int ks2 = 0; ks2 < 2; ++ks2)
#pragma unroll
            for (int ct = 0; ct < 4; ++ct)
                vr[ks2][ct] = *reinterpret_cast<const f16x8*>(
                    base + (2 * h + ks2) * 2048 + ct * 512);
    };
    // E phase (SWAPPED): lane lr holds row i = it*16+lr, cols j = w*16+4g+{0..3}
    // -> one packed f16x4 LDS write per it. live=false for the tail-clamped duplicate
    // call (chunk index 32) so l isn't double-counted.
    auto ephase = [&](const f16x8& k0, const f16x8& k1, char* dst, bool live) {
#pragma unroll
        for (int it = 0; it < 4; ++it) {
            f32x4 e = {0.f, 0.f, 0.f, 0.f};
            e = __builtin_amdgcn_mfma_f32_16x16x32_f16(k0, qf[it][0], e, 0, 0, 0);
            e = __builtin_amdgcn_mfma_f32_16x16x32_f16(k1, qf[it][1], e, 0, 0, 0);
            f16x4 p;
#pragma unroll
            for (int r = 0; r < 4; ++r)
                p[r] = (_Float16)exp2f((e[r] - mreg[it]) * L2E);
            if (live)
                lrun[it] += (float)p[0] + (float)p[1] + (float)p[2] + (float)p[3];
            const int i   = it * 16 + lr;
            const int off = (i * 256 + (w * 32 + 8 * g)) ^ ((i & 15) << 4);
            *reinterpret_cast<f16x4*>(dst + off) = p;
        }
    };
    auto pvhalf = [&](const char* src, int h, const f16x8 (&vr)[2][4]) {
        __builtin_amdgcn_s_setprio(1);
#pragma unroll
        for (int ks2 = 0; ks2 < 2; ++ks2) {
            const int ks = 2 * h + ks2;
            f16x8 pa[4];
#pragma unroll
            for (int it = 0; it < 4; ++it) {
                const int off = (it * 16 + lr) * 256 + ((ks * 64 + g * 16) ^ (lr << 4));
                pa[it] = *reinterpret_cast<const f16x8*>(src + off);
            }
#pragma unroll
            for (int it = 0; it < 4; ++it)
#pragma unroll
                for (int ct = 0; ct < 4; ++ct)
                    acc[it][ct] = __builtin_amdgcn_mfma_f32_16x16x32_f16(pa[it], vr[ks2][ct], acc[it][ct], 0, 0, 0);
        }
        __builtin_amdgcn_s_setprio(0);
    };

    auto region = [&](int t, char* rbuf, char* wbuf, f16x8& ku0, f16x8& ku1,
                      f16x8& kl0, f16x8& kl1) {
        ephase(ku0, ku1, wbuf, (t + 1) < 32);   // P(t+1) using K(t+1)
        loadK(t + 2, kl0, kl1);                 // K(t+2) into the other slot
        pvhalf(rbuf, 0, vA);                    // PV(t) ks 0-1
        loadVh(t + 1, 0, vA);                   // V(t+1) ks 0-1
        pvhalf(rbuf, 1, vB);                    // PV(t) ks 2-3
        loadVh(t + 1, 1, vB);                   // V(t+1) ks 2-3
        LDS_BARRIER();
    };

    // Prologue: P(0) -> pb0, V(0) -> vA/vB, K(1) -> kA.
    loadK(0, kA0, kA1);
    loadVh(0, 0, vA);
    loadVh(0, 1, vB);
    ephase(kA0, kA1, pb0, true);        // P(0) (uses K(0) in kA)
    loadK(1, kA0, kA1);                 // K(1) -> kA (K(0) dead)
    __syncthreads();

#pragma unroll 1
    for (int tp = 0; tp < 16; ++tp) {
        const int t = 2 * tp;
        region(t,     pb0, pb1, kA0, kA1, kB0, kB1);   // chunk t:   P in pb0, K(t+1)=kA
        region(t + 1, pb1, pb0, kB0, kB1, kA0, kA1);   // chunk t+1: P in pb1, K(t+2)=kB
    }
    // (final region's ephase is live=false; all 32 chunks PV'd and l-counted once)

    // ---- reduce l across g and waves ----
#pragma unroll
    for (int it = 0; it < 4; ++it) {
        float s = lrun[it];
#pragma unroll
        for (int mask = 16; mask < 64; mask <<= 1)
            s += __shfl_xor(s, mask, 64);
        if (g == 0)
            lmw[w * 64 + it * 16 + lr] = s;
    }
    __syncthreads();
    if (tid < 64) {
        float ss = 0.f;
#pragma unroll
        for (int w2 = 0; w2 < 8; ++w2) ss += lmw[w2 * 64 + tid];
        lfin[tid] = ss;
    }
    __syncthreads();

    // ---- epilogue: out = gamma * acc / l + x (l from LDS) ----
    const float gm = gamma[0];
#pragma unroll
    for (int it = 0; it < 4; ++it) {
        const int rb = it * 16 + 4 * g;     // local row base for this lane's acc
        const int idx = ib + rb;
        float inv[4];
#pragma unroll
        for (int r = 0; r < 4; ++r)
            inv[r] = 1.0f / lfin[rb + r];
#pragma unroll
        for (int ct = 0; ct < 4; ++ct) {
            const int c = cw + ct * 16 + lr;
            const size_t base = (size_t)(b * CDIM + c) * NPOS + idx;
            const float4 xv = *reinterpret_cast<const float4*>(x + base);
            float4 ov;
            ov.x = gm * (acc[it][ct][0] * inv[0]) + xv.x;
            ov.y = gm * (acc[it][ct][1] * inv[1]) + xv.y;
            ov.z = gm * (acc[it][ct][2] * inv[2]) + xv.z;
            ov.w = gm * (acc[it][ct][3] * inv[3]) + xv.w;
            *reinterpret_cast<float4*>(out + base) = ov;
        }
    }
}

extern "C" void kernel_launch(void* const* d_in, const int* in_sizes, int n_in,
                              void* d_out, int out_size, void* d_ws, size_t ws_size,
                              hipStream_t stream)
{
    (void)in_sizes; (void)n_in; (void)out_size; (void)ws_size;

    const float* x     = (const float*)d_in[0];
    const float* wq    = (const float*)d_in[1];
    const float* bq    = (const float*)d_in[2];
    const float* wk    = (const float*)d_in[3];
    const float* bk    = (const float*)d_in[4];
    const float* wv    = (const float*)d_in[5];
    const float* bv    = (const float*)d_in[6];
    const float* gamma = (const float*)d_in[7];
    float* out = (float*)d_out;

    char* ws = (char*)d_ws;
    const size_t qkBytes = (size_t)NBATCH * NPOS * CQK * sizeof(_Float16);     //  2 MiB each (K frag-ordered, same size)
    const size_t vBytes  = (size_t)NBATCH * CDIM * NPOS * sizeof(_Float16);    // 16 MiB (frag-ordered)
    const size_t xtBytes = (size_t)NBATCH * NPOS * CDIM * sizeof(_Float16);    // 16 MiB

    _Float16* Qp = (_Float16*)(ws);
    _Float16* Kp = (_Float16*)(ws + qkBytes);
    _Float16* Vp = (_Float16*)(ws + 2 * qkBytes);
    _Float16* Xt = (_Float16*)(ws + 2 * qkBytes + vBytes);
    _Float16* Wh = (_Float16*)(ws + 2 * qkBytes + vBytes + xtBytes);
    float* biasc = (float*)(ws + 2 * qkBytes + vBytes + xtBytes
                              + (size_t)640 * CDIM * sizeof(_Float16));
    // total ws use ~= 36.6 MiB

    x_cvt_kernel<<<dim3(NPOS / 64, CDIM / 64, NBATCH), 256, 0, stream>>>(
        x, Xt, wq, bq, wk, bk, wv, bv, Wh, biasc);
    proj_gemm_kernel<<<dim3(NPOS / 128, 5, NBATCH), 256, 0, stream>>>(Wh, biasc, Xt, Qp, Kp, Vp);
    attn_fused_kernel<<<dim3(NPOS / 64 * NBATCH), 512, 0, stream>>>(x, Qp, Kp, Vp, gamma, out);
}

// Round 25
// 125.122 us; speedup vs baseline: 2.4760x; 1.0238x over previous
//
#include <hip/hip_runtime.h>
#include <hip/hip_fp16.h>

#define NPOS   4096
#define CDIM   512
#define CQK    64
#define NBATCH 4
#define L2E 1.44269504088896f

typedef _Float16 f16x8 __attribute__((ext_vector_type(8)));
typedef _Float16 f16x4 __attribute__((ext_vector_type(4)));
typedef float    f32x4 __attribute__((ext_vector_type(4)));

// LDS-only drain barrier: keeps global-load (vmcnt) prefetches in flight across
// the barrier (T4). All cross-wave traffic here is LDS, so lgkmcnt(0) suffices.
#define LDS_BARRIER() asm volatile("s_waitcnt lgkmcnt(0)\ns_barrier" ::: "memory")

// ---------------- x convert+transpose (+ fused weight convert) ----------------
// (R20 structure — measured best; unchanged.)
__global__ __launch_bounds__(256) void x_cvt_kernel(
    const float* __restrict__ x, _Float16* __restrict__ Xt,
    const float* __restrict__ wq, const float* __restrict__ bq,
    const float* __restrict__ wk, const float* __restrict__ bk,
    const float* __restrict__ wv, const float* __restrict__ bv,
    _Float16* __restrict__ Wh, float* __restrict__ biasc)
{
    __shared__ _Float16 tile[64][66];
    const int b  = blockIdx.z;
    const int c0 = blockIdx.y * 64;
    const int n0 = blockIdx.x * 64;
    const int tid = threadIdx.x;

    if (blockIdx.z == 0 && blockIdx.y == 0) {
        const int gid = blockIdx.x * 256 + tid;          // 0..16383
#pragma unroll 1
        for (int idx4 = gid; idx4 < 640 * CDIM / 4; idx4 += 64 * 256) {
            const int idx = idx4 * 4;
            const float* src;
            if (idx < 64 * 512)       src = wq + idx;
            else if (idx < 128 * 512) src = wk + (idx - 64 * 512);
            else                      src = wv + (idx - 128 * 512);
            const float4 v = *reinterpret_cast<const float4*>(src);
            f16x4 h;
            h[0] = (_Float16)v.x; h[1] = (_Float16)v.y;
            h[2] = (_Float16)v.z; h[3] = (_Float16)v.w;
            *reinterpret_cast<f16x4*>(Wh + idx) = h;
        }
        if (gid < 640) {
            float bb;
            if (gid < 64)       bb = bq[gid];
            else if (gid < 128) bb = bk[gid - 64];
            else                bb = bv[gid - 128];
            biasc[gid] = bb;
        }
    }

    const int rr = tid >> 4;
    const int n4 = (tid & 15) * 4;
#pragma unroll
    for (int i = 0; i < 4; ++i) {
        const int c = i * 16 + rr;
        const float4 v = *reinterpret_cast<const float4*>(
            x + (size_t)(b * CDIM + c0 + c) * NPOS + n0 + n4);
        tile[c][n4 + 0] = (_Float16)v.x;
        tile[c][n4 + 1] = (_Float16)v.y;
        tile[c][n4 + 2] = (_Float16)v.z;
        tile[c][n4 + 3] = (_Float16)v.w;
    }
    __syncthreads();

    const int col = tid & 63;
    const int r4  = tid >> 6;
#pragma unroll
    for (int i = 0; i < 16; ++i) {
        const int n = i * 4 + r4;
        Xt[((size_t)b * NPOS + n0 + n) * CDIM + c0 + col] = tile[col][n];
    }
}

// ---------------- fused QKV projection GEMM: 128x128 tile, LDS double-buffered ----------------
// (R24 structure: R13 GEMM core + frag-ordered K/V epilogues; unchanged.)
__global__ __launch_bounds__(256) void proj_gemm_kernel(
    const _Float16* __restrict__ Wh, const float* __restrict__ biasc,
    const _Float16* __restrict__ Xt,
    _Float16* __restrict__ Qp, _Float16* __restrict__ Kp, _Float16* __restrict__ Vp)
{
    __shared__ __align__(16) _Float16 As[2][128 * 32];
    __shared__ __align__(16) _Float16 Bs[2][128 * 32];

    const int tid  = threadIdx.x;
    const int lane = tid & 63;
    const int w    = tid >> 6;       // 0..3
    const int wr   = w >> 1;         // m-half
    const int wc   = w & 1;          // n-half
    const int g    = lane >> 4;
    const int lr   = lane & 15;

    const int b  = blockIdx.z;
    const int m0 = blockIdx.y * 128;
    const int n0 = blockIdx.x * 128;

    const _Float16* xb = Xt + (size_t)b * NPOS * CDIM;

    const int srow = tid >> 2;
    const int schk = (tid & 3) * 8;

    f16x8 sA[2], sB[2];
    auto gload = [&](int kk) {
#pragma unroll
        for (int rnd = 0; rnd < 2; ++rnd) {
            const int row = srow + rnd * 64;
            sA[rnd] = *reinterpret_cast<const f16x8*>(
                Wh + (size_t)(m0 + row) * CDIM + kk + schk);
            sB[rnd] = *reinterpret_cast<const f16x8*>(
                xb + (size_t)(n0 + row) * CDIM + kk + schk);
        }
    };
    auto dswrite = [&](int buf) {
#pragma unroll
        for (int rnd = 0; rnd < 2; ++rnd) {
            const int row = srow + rnd * 64;
            *reinterpret_cast<f16x8*>(&As[buf][row * 32 + schk]) = sA[rnd];
            *reinterpret_cast<f16x8*>(&Bs[buf][row * 32 + schk]) = sB[rnd];
        }
    };

    f32x4 acc[4][4];
#pragma unroll
    for (int it = 0; it < 4; ++it)
#pragma unroll
        for (int ct = 0; ct < 4; ++ct) {
            f32x4 z = {0.f, 0.f, 0.f, 0.f};
            acc[it][ct] = z;
        }

    auto compute = [&](int buf) {
        f16x8 a[4], bf[4];
#pragma unroll
        for (int it = 0; it < 4; ++it)
            a[it] = *reinterpret_cast<const f16x8*>(
                &As[buf][(wr * 64 + it * 16 + lr) * 32 + 8 * g]);
#pragma unroll
        for (int ct = 0; ct < 4; ++ct)
            bf[ct] = *reinterpret_cast<const f16x8*>(
                &Bs[buf][(wc * 64 + ct * 16 + lr) * 32 + 8 * g]);
#pragma unroll
        for (int it = 0; it < 4; ++it)
#pragma unroll
            for (int ct = 0; ct < 4; ++ct)
                acc[it][ct] = __builtin_amdgcn_mfma_f32_16x16x32_f16(a[it], bf[ct], acc[it][ct], 0, 0, 0);
    };

    gload(0);
    dswrite(0);
    __syncthreads();

#pragma unroll 1
    for (int t = 0; t < 16; ++t) {
        if (t < 15) gload((t + 1) * 32);
        compute(t & 1);
        if (t < 15) dswrite((t + 1) & 1);
        __syncthreads();
    }

    if (m0 == 0) {
        if (wr == 0) {
            // Q rows 0..63 — layout unchanged ([n][o], consumed once per block)
#pragma unroll
            for (int it = 0; it < 4; ++it) {
                const int gmb = it * 16 + 4 * g;
#pragma unroll
                for (int ct = 0; ct < 4; ++ct) {
                    const int n = n0 + wc * 64 + ct * 16 + lr;
                    f16x4 h;
#pragma unroll
                    for (int r = 0; r < 4; ++r)
                        h[r] = (_Float16)(acc[it][ct][r] + biasc[gmb + r]);
                    *reinterpret_cast<f16x4*>(Qp + ((size_t)b * NPOS + n) * CQK + gmb) = h;
                }
            }
        } else {
            // K rows 64..127 — FRAG-ORDERED: Kf[b][s][chunk][lane'][e]
#pragma unroll
            for (int it = 0; it < 4; ++it) {
                const int o0    = it * 16 + 4 * g;      // o = o0 + r
                const int gmb   = 64 + o0;              // bias index
                const int chunk = o0 >> 5;
                const int gp    = (o0 & 31) >> 3;
                const int e0    = o0 & 7;               // 0 or 4
#pragma unroll
                for (int ct = 0; ct < 4; ++ct) {
                    const int n  = n0 + wc * 64 + ct * 16 + lr;
                    const int s  = n >> 4;
                    const int jl = n & 15;
                    f16x4 h;
#pragma unroll
                    for (int r = 0; r < 4; ++r)
                        h[r] = (_Float16)(acc[it][ct][r] + biasc[gmb + r]);
                    const size_t idx =
                        ((((size_t)b * 256 + s) * 2 + chunk) * 64 + gp * 16 + jl) * 8 + e0;
                    *reinterpret_cast<f16x4*>(Kp + idx) = h;
                }
            }
        }
    } else {
        const int cb = ((m0 - 128) >> 6) + wr;
        const int t  = n0 >> 7;
#pragma unroll
        for (int it = 0; it < 4; ++it) {
            const int gmb = m0 + wr * 64 + it * 16 + 4 * g;
#pragma unroll
            for (int ct = 0; ct < 4; ++ct) {
                const int ks = wc * 2 + (ct >> 1);
                const int ga = (ct * 2 + (lr >> 3)) & 3;
                const int e  = lr & 7;
#pragma unroll
                for (int r = 0; r < 4; ++r) {
                    const int lra = 4 * g + r;
                    const size_t idx =
                        ((((((size_t)b * 8 + cb) * 32 + t) * 4 + ks) * 4 + it) * 4 + ga) * 16 + lra;
                    Vp[idx * 8 + e] = (_Float16)(acc[it][ct][r] + biasc[gmb + r]);
                }
            }
        }
    }
}

// ---------------- Fused attention: pass 1 (row MAX only) + pass 2 (flash PV + l-from-P) ----------------
// R24 structure; VALU trims: (1) lrun accumulated from the live f32 exp2 results
// (removes 16 f16->f32 converts per ephase; l now sums f32 exps — rel shift <= 2^-11,
// far inside threshold), (2) pass-1 running max written in v_max3-fusable form.
__global__ __launch_bounds__(512, 2) void attn_fused_kernel(
    const float* __restrict__ x, const _Float16* __restrict__ Qp, const _Float16* __restrict__ Kp,
    const _Float16* __restrict__ Vp, const float* __restrict__ gamma, float* __restrict__ out)
{
    __shared__ __align__(16) _Float16 Pl[2][64 * 128];
    __shared__ float lmw[8 * 64];
    __shared__ float mfin[64];
    __shared__ float lfin[64];
    char* pb0 = (char*)Pl[0];
    char* pb1 = (char*)Pl[1];

    const int tid  = threadIdx.x;
    const int lane = tid & 63;
    const int w    = tid >> 6;      // 0..7
    const int g    = lane >> 4;     // 0..3
    const int lr   = lane & 15;

    // XCD-aware decode: batch b -> XCDs {2b,2b+1} so each XCD L2 holds one batch's V+K.
    const int bid = blockIdx.x;
    const int b   = (bid & 7) >> 1;
    const int ib  = (((bid >> 3) << 1) | (bid & 1)) * 64;
    const int cw  = w * 64;

    const _Float16* kb  = Kp + (size_t)b * 262144;           // frag-ordered K
    const _Float16* vbw = Vp + ((size_t)b * 8 + w) * 262144; // frag-ordered V (per-wave c-block)

    f16x8 qf[4][2];
#pragma unroll
    for (int it = 0; it < 4; ++it)
#pragma unroll
        for (int ks = 0; ks < 2; ++ks)
            qf[it][ks] = *reinterpret_cast<const f16x8*>(
                Qp + (b * NPOS + ib + it * 16 + lr) * CQK + ks * 32 + 8 * g);

    f16x8 kA0, kA1, kB0, kB1;   // 2-slot K prefetch (pass 2)
    // frag-ordered K read: fully coalesced (uniform base + lane*16B)
    auto loadK = [&](int t, f16x8& k0, f16x8& k1) {
        const int tc = (t < 32) ? t : 31;
        const _Float16* p = kb + ((size_t)(tc * 8 + w) * 2) * 512 + lane * 8;
        k0 = *reinterpret_cast<const f16x8*>(p);
        k1 = *reinterpret_cast<const f16x8*>(p + 512);
    };

    // ======== PASS 1: row max only (v_max3-fusable fmax trees) ========
    {
        float mrun[4];
#pragma unroll
        for (int it = 0; it < 4; ++it) mrun[it] = -1e30f;

        auto step = [&](const f16x8& k0, const f16x8& k1) {
#pragma unroll
            for (int it = 0; it < 4; ++it) {
                f32x4 e = {0.f, 0.f, 0.f, 0.f};
                e = __builtin_amdgcn_mfma_f32_16x16x32_f16(k0, qf[it][0], e, 0, 0, 0);
                e = __builtin_amdgcn_mfma_f32_16x16x32_f16(k1, qf[it][1], e, 0, 0, 0);
                // two v_max3-shaped reductions: max3(e0,e1,m), then max3(e2,e3,that)
                mrun[it] = fmaxf(fmaxf(e[2], e[3]),
                                 fmaxf(fmaxf(e[0], e[1]), mrun[it]));
            }
        };

        loadK(0, kA0, kA1);
#pragma unroll 1
        for (int tp = 0; tp < 16; ++tp) {
            const int t = 2 * tp;
            loadK(t + 1, kB0, kB1);
            step(kA0, kA1);
            loadK(t + 2, kA0, kA1);
            step(kB0, kB1);
        }

        // reduce across g (lanes lr, lr+16, lr+32, lr+48), then across waves via LDS
#pragma unroll
        for (int it = 0; it < 4; ++it) {
            float m = mrun[it];
#pragma unroll
            for (int mask = 16; mask < 64; mask <<= 1)
                m = fmaxf(m, __shfl_xor(m, mask, 64));
            if (g == 0)
                lmw[w * 64 + it * 16 + lr] = m;
        }
        __syncthreads();

        if (tid < 64) {
            float mm = lmw[tid];
#pragma unroll
            for (int w2 = 1; w2 < 8; ++w2) mm = fmaxf(mm, lmw[w2 * 64 + tid]);
            mfin[tid] = mm;
        }
        __syncthreads();
    }

    // m for row i = ib + it*16 + lr
    float mreg[4];
#pragma unroll
    for (int it = 0; it < 4; ++it)
        mreg[it] = mfin[it * 16 + lr];

    // ======== PASS 2: flash PV (R16 schedule) + l accumulation from f32 exps ========
    f32x4 acc[4][4];
#pragma unroll
    for (int it = 0; it < 4; ++it)
#pragma unroll
        for (int ct = 0; ct < 4; ++ct) {
            f32x4 z = {0.f, 0.f, 0.f, 0.f};
            acc[it][ct] = z;
        }

    float lrun[4] = {0.f, 0.f, 0.f, 0.f};   // per-lane partial sums of exp (f32)
    f16x8 vA[2][4], vB[2][4];   // half-chunk V buffers (ks 0-1 / ks 2-3), 32 VGPR each

    // frag-ordered V read: fully coalesced (uniform base + lane*16B)
    auto loadVh = [&](int t, int h, f16x8 (&vr)[2][4]) {
        const int tc = (t < 32) ? t : 31;
        const _Float16* base = vbw + (size_t)tc * 8192 + lane * 8;
#pragma unroll
        for (int ks2 = 0; ks2 < 2; ++ks2)
#pragma unroll
            for (int ct = 0; ct < 4; ++ct)
                vr[ks2][ct] = *reinterpret_cast<const f16x8*>(
                    base + (2 * h + ks2) * 2048 + ct * 512);
    };
    // E phase (SWAPPED): lane lr holds row i = it*16+lr, cols j = w*16+4g+{0..3}
    // -> one packed f16x4 LDS write per it. live=false for the tail-clamped duplicate
    // call (chunk index 32) so l isn't double-counted.
    auto ephase = [&](const f16x8& k0, const f16x8& k1, char* dst, bool live) {
#pragma unroll
        for (int it = 0; it < 4; ++it) {
            f32x4 e = {0.f, 0.f, 0.f, 0.f};
            e = __builtin_amdgcn_mfma_f32_16x16x32_f16(k0, qf[it][0], e, 0, 0, 0);
            e = __builtin_amdgcn_mfma_f32_16x16x32_f16(k1, qf[it][1], e, 0, 0, 0);
            float x0 = exp2f((e[0] - mreg[it]) * L2E);
            float x1 = exp2f((e[1] - mreg[it]) * L2E);
            float x2 = exp2f((e[2] - mreg[it]) * L2E);
            float x3 = exp2f((e[3] - mreg[it]) * L2E);
            if (live)
                lrun[it] += (x0 + x1) + (x2 + x3);
            f16x4 p;
            p[0] = (_Float16)x0; p[1] = (_Float16)x1;
            p[2] = (_Float16)x2; p[3] = (_Float16)x3;
            const int i   = it * 16 + lr;
            const int off = (i * 256 + (w * 32 + 8 * g)) ^ ((i & 15) << 4);
            *reinterpret_cast<f16x4*>(dst + off) = p;
        }
    };
    auto pvhalf = [&](const char* src, int h, const f16x8 (&vr)[2][4]) {
        __builtin_amdgcn_s_setprio(1);
#pragma unroll
        for (int ks2 = 0; ks2 < 2; ++ks2) {
            const int ks = 2 * h + ks2;
            f16x8 pa[4];
#pragma unroll
            for (int it = 0; it < 4; ++it) {
                const int off = (it * 16 + lr) * 256 + ((ks * 64 + g * 16) ^ (lr << 4));
                pa[it] = *reinterpret_cast<const f16x8*>(src + off);
            }
#pragma unroll
            for (int it = 0; it < 4; ++it)
#pragma unroll
                for (int ct = 0; ct < 4; ++ct)
                    acc[it][ct] = __builtin_amdgcn_mfma_f32_16x16x32_f16(pa[it], vr[ks2][ct], acc[it][ct], 0, 0, 0);
        }
        __builtin_amdgcn_s_setprio(0);
    };

    auto region = [&](int t, char* rbuf, char* wbuf, f16x8& ku0, f16x8& ku1,
                      f16x8& kl0, f16x8& kl1) {
        ephase(ku0, ku1, wbuf, (t + 1) < 32);   // P(t+1) using K(t+1)
        loadK(t + 2, kl0, kl1);                 // K(t+2) into the other slot
        pvhalf(rbuf, 0, vA);                    // PV(t) ks 0-1
        loadVh(t + 1, 0, vA);                   // V(t+1) ks 0-1
        pvhalf(rbuf, 1, vB);                    // PV(t) ks 2-3
        loadVh(t + 1, 1, vB);                   // V(t+1) ks 2-3
        LDS_BARRIER();
    };

    // Prologue: P(0) -> pb0, V(0) -> vA/vB, K(1) -> kA.
    loadK(0, kA0, kA1);
    loadVh(0, 0, vA);
    loadVh(0, 1, vB);
    ephase(kA0, kA1, pb0, true);        // P(0) (uses K(0) in kA)
    loadK(1, kA0, kA1);                 // K(1) -> kA (K(0) dead)
    __syncthreads();

#pragma unroll 1
    for (int tp = 0; tp < 16; ++tp) {
        const int t = 2 * tp;
        region(t,     pb0, pb1, kA0, kA1, kB0, kB1);   // chunk t:   P in pb0, K(t+1)=kA
        region(t + 1, pb1, pb0, kB0, kB1, kA0, kA1);   // chunk t+1: P in pb1, K(t+2)=kB
    }
    // (final region's ephase is live=false; all 32 chunks PV'd and l-counted once)

    // ---- reduce l across g and waves ----
#pragma unroll
    for (int it = 0; it < 4; ++it) {
        float s = lrun[it];
#pragma unroll
        for (int mask = 16; mask < 64; mask <<= 1)
            s += __shfl_xor(s, mask, 64);
        if (g == 0)
            lmw[w * 64 + it * 16 + lr] = s;
    }
    __syncthreads();
    if (tid < 64) {
        float ss = 0.f;
#pragma unroll
        for (int w2 = 0; w2 < 8; ++w2) ss += lmw[w2 * 64 + tid];
        lfin[tid] = ss;
    }
    __syncthreads();

    // ---- epilogue: out = gamma * acc / l + x (l from LDS) ----
    const float gm = gamma[0];
#pragma unroll
    for (int it = 0; it < 4; ++it) {
        const int rb = it * 16 + 4 * g;     // local row base for this lane's acc
        const int idx = ib + rb;
        float inv[4];
#pragma unroll
        for (int r = 0; r < 4; ++r)
            inv[r] = 1.0f / lfin[rb + r];
#pragma unroll
        for (int ct = 0; ct < 4; ++ct) {
            const int c = cw + ct * 16 + lr;
            const size_t base = (size_t)(b * CDIM + c) * NPOS + idx;
            const float4 xv = *reinterpret_cast<const float4*>(x + base);
            float4 ov;
            ov.x = gm * (acc[it][ct][0] * inv[0]) + xv.x;
            ov.y = gm * (acc[it][ct][1] * inv[1]) + xv.y;
            ov.z = gm * (acc[it][ct][2] * inv[2]) + xv.z;
            ov.w = gm * (acc[it][ct][3] * inv[3]) + xv.w;
            *reinterpret_cast<float4*>(out + base) = ov;
        }
    }
}

extern "C" void kernel_launch(void* const* d_in, const int* in_sizes, int n_in,
                              void* d_out, int out_size, void* d_ws, size_t ws_size,
                              hipStream_t stream)
{
    (void)in_sizes; (void)n_in; (void)out_size; (void)ws_size;

    const float* x     = (const float*)d_in[0];
    const float* wq    = (const float*)d_in[1];
    const float* bq    = (const float*)d_in[2];
    const float* wk    = (const float*)d_in[3];
    const float* bk    = (const float*)d_in[4];
    const float* wv    = (const float*)d_in[5];
    const float* bv    = (const float*)d_in[6];
    const float* gamma = (const float*)d_in[7];
    float* out = (float*)d_out;

    char* ws = (char*)d_ws;
    const size_t qkBytes = (size_t)NBATCH * NPOS * CQK * sizeof(_Float16);     //  2 MiB each (K frag-ordered, same size)
    const size_t vBytes  = (size_t)NBATCH * CDIM * NPOS * sizeof(_Float16);    // 16 MiB (frag-ordered)
    const size_t xtBytes = (size_t)NBATCH * NPOS * CDIM * sizeof(_Float16);    // 16 MiB

    _Float16* Qp = (_Float16*)(ws);
    _Float16* Kp = (_Float16*)(ws + qkBytes);
    _Float16* Vp = (_Float16*)(ws + 2 * qkBytes);
    _Float16* Xt = (_Float16*)(ws + 2 * qkBytes + vBytes);
    _Float16* Wh = (_Float16*)(ws + 2 * qkBytes + vBytes + xtBytes);
    float* biasc = (float*)(ws + 2 * qkBytes + vBytes + xtBytes
                              + (size_t)640 * CDIM * sizeof(_Float16));
    // total ws use ~= 36.6 MiB

    x_cvt_kernel<<<dim3(NPOS / 64, CDIM / 64, NBATCH), 256, 0, stream>>>(
        x, Xt, wq, bq, wk, bk, wv, bv, Wh, biasc);
    proj_gemm_kernel<<<dim3(NPOS / 128, 5, NBATCH), 256, 0, stream>>>(Wh, biasc, Xt, Qp, Kp, Vp);
    attn_fused_kernel<<<dim3(NPOS / 64 * NBATCH), 512, 0, stream>>>(x, Qp, Kp, Vp, gamma, out);
}

// Round 26
// 124.821 us; speedup vs baseline: 2.4820x; 1.0024x over previous
//
#include <hip/hip_runtime.h>
#include <hip/hip_fp16.h>

#define NPOS   4096
#define CDIM   512
#define CQK    64
#define NBATCH 4
#define L2E 1.44269504088896f

typedef _Float16 f16x8 __attribute__((ext_vector_type(8)));
typedef _Float16 f16x4 __attribute__((ext_vector_type(4)));
typedef float    f32x4 __attribute__((ext_vector_type(4)));

// LDS-only drain barrier: keeps global-load (vmcnt) prefetches in flight across
// the barrier (T4). All cross-wave traffic here is LDS, so lgkmcnt(0) suffices.
#define LDS_BARRIER() asm volatile("s_waitcnt lgkmcnt(0)\ns_barrier" ::: "memory")

// ---------------- x convert+transpose (+ fused weight convert) ----------------
// x[b,c,n] f32 -> Xt[b,n,c] f16 via padded LDS tile. Writer re-mapped: each thread
// owns 8 consecutive c at fixed n -> ONE 16B f16x8 global store (1KB/wave-instr,
// was 16 scalar 2B stores = 128B/wave-instr). LDS octet reads alias 2-way (free).
// Values bitwise identical to the old kernel. W-convert part unchanged.
__global__ __launch_bounds__(256) void x_cvt_kernel(
    const float* __restrict__ x, _Float16* __restrict__ Xt,
    const float* __restrict__ wq, const float* __restrict__ bq,
    const float* __restrict__ wk, const float* __restrict__ bk,
    const float* __restrict__ wv, const float* __restrict__ bv,
    _Float16* __restrict__ Wh, float* __restrict__ biasc)
{
    __shared__ _Float16 tile[64][66];
    const int b  = blockIdx.z;
    const int c0 = blockIdx.y * 64;
    const int n0 = blockIdx.x * 64;
    const int tid = threadIdx.x;

    if (blockIdx.z == 0 && blockIdx.y == 0) {
        const int gid = blockIdx.x * 256 + tid;          // 0..16383
#pragma unroll 1
        for (int idx4 = gid; idx4 < 640 * CDIM / 4; idx4 += 64 * 256) {
            const int idx = idx4 * 4;
            const float* src;
            if (idx < 64 * 512)       src = wq + idx;
            else if (idx < 128 * 512) src = wk + (idx - 64 * 512);
            else                      src = wv + (idx - 128 * 512);
            const float4 v = *reinterpret_cast<const float4*>(src);
            f16x4 h;
            h[0] = (_Float16)v.x; h[1] = (_Float16)v.y;
            h[2] = (_Float16)v.z; h[3] = (_Float16)v.w;
            *reinterpret_cast<f16x4*>(Wh + idx) = h;
        }
        if (gid < 640) {
            float bb;
            if (gid < 64)       bb = bq[gid];
            else if (gid < 128) bb = bk[gid - 64];
            else                bb = bv[gid - 128];
            biasc[gid] = bb;
        }
    }

    const int rr = tid >> 4;
    const int n4 = (tid & 15) * 4;
#pragma unroll
    for (int i = 0; i < 4; ++i) {
        const int c = i * 16 + rr;
        const float4 v = *reinterpret_cast<const float4*>(
            x + (size_t)(b * CDIM + c0 + c) * NPOS + n0 + n4);
        tile[c][n4 + 0] = (_Float16)v.x;
        tile[c][n4 + 1] = (_Float16)v.y;
        tile[c][n4 + 2] = (_Float16)v.z;
        tile[c][n4 + 3] = (_Float16)v.w;
    }
    __syncthreads();

    // writer: thread item -> (n, c-octet); one f16x8 (16B) coalesced store each
#pragma unroll
    for (int q = 0; q < 2; ++q) {
        const int item = q * 256 + tid;       // 0..511
        const int n    = item >> 3;           // 0..63
        const int oct  = (item & 7) * 8;      // c octet base
        f16x8 h;
#pragma unroll
        for (int e = 0; e < 8; ++e)
            h[e] = tile[oct + e][n];
        *reinterpret_cast<f16x8*>(
            Xt + ((size_t)b * NPOS + n0 + n) * CDIM + c0 + oct) = h;
    }
}

// ---------------- fused QKV projection GEMM: 128x128 tile, LDS double-buffered ----------------
// (R24 structure: R13 GEMM core + frag-ordered K/V epilogues; unchanged.)
__global__ __launch_bounds__(256) void proj_gemm_kernel(
    const _Float16* __restrict__ Wh, const float* __restrict__ biasc,
    const _Float16* __restrict__ Xt,
    _Float16* __restrict__ Qp, _Float16* __restrict__ Kp, _Float16* __restrict__ Vp)
{
    __shared__ __align__(16) _Float16 As[2][128 * 32];
    __shared__ __align__(16) _Float16 Bs[2][128 * 32];

    const int tid  = threadIdx.x;
    const int lane = tid & 63;
    const int w    = tid >> 6;       // 0..3
    const int wr   = w >> 1;         // m-half
    const int wc   = w & 1;          // n-half
    const int g    = lane >> 4;
    const int lr   = lane & 15;

    const int b  = blockIdx.z;
    const int m0 = blockIdx.y * 128;
    const int n0 = blockIdx.x * 128;

    const _Float16* xb = Xt + (size_t)b * NPOS * CDIM;

    const int srow = tid >> 2;
    const int schk = (tid & 3) * 8;

    f16x8 sA[2], sB[2];
    auto gload = [&](int kk) {
#pragma unroll
        for (int rnd = 0; rnd < 2; ++rnd) {
            const int row = srow + rnd * 64;
            sA[rnd] = *reinterpret_cast<const f16x8*>(
                Wh + (size_t)(m0 + row) * CDIM + kk + schk);
            sB[rnd] = *reinterpret_cast<const f16x8*>(
                xb + (size_t)(n0 + row) * CDIM + kk + schk);
        }
    };
    auto dswrite = [&](int buf) {
#pragma unroll
        for (int rnd = 0; rnd < 2; ++rnd) {
            const int row = srow + rnd * 64;
            *reinterpret_cast<f16x8*>(&As[buf][row * 32 + schk]) = sA[rnd];
            *reinterpret_cast<f16x8*>(&Bs[buf][row * 32 + schk]) = sB[rnd];
        }
    };

    f32x4 acc[4][4];
#pragma unroll
    for (int it = 0; it < 4; ++it)
#pragma unroll
        for (int ct = 0; ct < 4; ++ct) {
            f32x4 z = {0.f, 0.f, 0.f, 0.f};
            acc[it][ct] = z;
        }

    auto compute = [&](int buf) {
        f16x8 a[4], bf[4];
#pragma unroll
        for (int it = 0; it < 4; ++it)
            a[it] = *reinterpret_cast<const f16x8*>(
                &As[buf][(wr * 64 + it * 16 + lr) * 32 + 8 * g]);
#pragma unroll
        for (int ct = 0; ct < 4; ++ct)
            bf[ct] = *reinterpret_cast<const f16x8*>(
                &Bs[buf][(wc * 64 + ct * 16 + lr) * 32 + 8 * g]);
#pragma unroll
        for (int it = 0; it < 4; ++it)
#pragma unroll
            for (int ct = 0; ct < 4; ++ct)
                acc[it][ct] = __builtin_amdgcn_mfma_f32_16x16x32_f16(a[it], bf[ct], acc[it][ct], 0, 0, 0);
    };

    gload(0);
    dswrite(0);
    __syncthreads();

#pragma unroll 1
    for (int t = 0; t < 16; ++t) {
        if (t < 15) gload((t + 1) * 32);
        compute(t & 1);
        if (t < 15) dswrite((t + 1) & 1);
        __syncthreads();
    }

    if (m0 == 0) {
        if (wr == 0) {
            // Q rows 0..63 — layout unchanged ([n][o], consumed once per block)
#pragma unroll
            for (int it = 0; it < 4; ++it) {
                const int gmb = it * 16 + 4 * g;
#pragma unroll
                for (int ct = 0; ct < 4; ++ct) {
                    const int n = n0 + wc * 64 + ct * 16 + lr;
                    f16x4 h;
#pragma unroll
                    for (int r = 0; r < 4; ++r)
                        h[r] = (_Float16)(acc[it][ct][r] + biasc[gmb + r]);
                    *reinterpret_cast<f16x4*>(Qp + ((size_t)b * NPOS + n) * CQK + gmb) = h;
                }
            }
        } else {
            // K rows 64..127 — FRAG-ORDERED: Kf[b][s][chunk][lane'][e]
#pragma unroll
            for (int it = 0; it < 4; ++it) {
                const int o0    = it * 16 + 4 * g;      // o = o0 + r
                const int gmb   = 64 + o0;              // bias index
                const int chunk = o0 >> 5;
                const int gp    = (o0 & 31) >> 3;
                const int e0    = o0 & 7;               // 0 or 4
#pragma unroll
                for (int ct = 0; ct < 4; ++ct) {
                    const int n  = n0 + wc * 64 + ct * 16 + lr;
                    const int s  = n >> 4;
                    const int jl = n & 15;
                    f16x4 h;
#pragma unroll
                    for (int r = 0; r < 4; ++r)
                        h[r] = (_Float16)(acc[it][ct][r] + biasc[gmb + r]);
                    const size_t idx =
                        ((((size_t)b * 256 + s) * 2 + chunk) * 64 + gp * 16 + jl) * 8 + e0;
                    *reinterpret_cast<f16x4*>(Kp + idx) = h;
                }
            }
        }
    } else {
        const int cb = ((m0 - 128) >> 6) + wr;
        const int t  = n0 >> 7;
#pragma unroll
        for (int it = 0; it < 4; ++it) {
            const int gmb = m0 + wr * 64 + it * 16 + 4 * g;
#pragma unroll
            for (int ct = 0; ct < 4; ++ct) {
                const int ks = wc * 2 + (ct >> 1);
                const int ga = (ct * 2 + (lr >> 3)) & 3;
                const int e  = lr & 7;
#pragma unroll
                for (int r = 0; r < 4; ++r) {
                    const int lra = 4 * g + r;
                    const size_t idx =
                        ((((((size_t)b * 8 + cb) * 32 + t) * 4 + ks) * 4 + it) * 4 + ga) * 16 + lra;
                    Vp[idx * 8 + e] = (_Float16)(acc[it][ct][r] + biasc[gmb + r]);
                }
            }
        }
    }
}

// ---------------- Fused attention: pass 1 (row MAX only) + pass 2 (flash PV + l-from-P) ----------------
// (R25 structure — best measured; unchanged.)
__global__ __launch_bounds__(512, 2) void attn_fused_kernel(
    const float* __restrict__ x, const _Float16* __restrict__ Qp, const _Float16* __restrict__ Kp,
    const _Float16* __restrict__ Vp, const float* __restrict__ gamma, float* __restrict__ out)
{
    __shared__ __align__(16) _Float16 Pl[2][64 * 128];
    __shared__ float lmw[8 * 64];
    __shared__ float mfin[64];
    __shared__ float lfin[64];
    char* pb0 = (char*)Pl[0];
    char* pb1 = (char*)Pl[1];

    const int tid  = threadIdx.x;
    const int lane = tid & 63;
    const int w    = tid >> 6;      // 0..7
    const int g    = lane >> 4;     // 0..3
    const int lr   = lane & 15;

    // XCD-aware decode: batch b -> XCDs {2b,2b+1} so each XCD L2 holds one batch's V+K.
    const int bid = blockIdx.x;
    const int b   = (bid & 7) >> 1;
    const int ib  = (((bid >> 3) << 1) | (bid & 1)) * 64;
    const int cw  = w * 64;

    const _Float16* kb  = Kp + (size_t)b * 262144;           // frag-ordered K
    const _Float16* vbw = Vp + ((size_t)b * 8 + w) * 262144; // frag-ordered V (per-wave c-block)

    f16x8 qf[4][2];
#pragma unroll
    for (int it = 0; it < 4; ++it)
#pragma unroll
        for (int ks = 0; ks < 2; ++ks)
            qf[it][ks] = *reinterpret_cast<const f16x8*>(
                Qp + (b * NPOS + ib + it * 16 + lr) * CQK + ks * 32 + 8 * g);

    f16x8 kA0, kA1, kB0, kB1;   // 2-slot K prefetch (pass 2)
    // frag-ordered K read: fully coalesced (uniform base + lane*16B)
    auto loadK = [&](int t, f16x8& k0, f16x8& k1) {
        const int tc = (t < 32) ? t : 31;
        const _Float16* p = kb + ((size_t)(tc * 8 + w) * 2) * 512 + lane * 8;
        k0 = *reinterpret_cast<const f16x8*>(p);
        k1 = *reinterpret_cast<const f16x8*>(p + 512);
    };

    // ======== PASS 1: row max only (v_max3-fusable fmax trees) ========
    {
        float mrun[4];
#pragma unroll
        for (int it = 0; it < 4; ++it) mrun[it] = -1e30f;

        auto step = [&](const f16x8& k0, const f16x8& k1) {
#pragma unroll
            for (int it = 0; it < 4; ++it) {
                f32x4 e = {0.f, 0.f, 0.f, 0.f};
                e = __builtin_amdgcn_mfma_f32_16x16x32_f16(k0, qf[it][0], e, 0, 0, 0);
                e = __builtin_amdgcn_mfma_f32_16x16x32_f16(k1, qf[it][1], e, 0, 0, 0);
                mrun[it] = fmaxf(fmaxf(e[2], e[3]),
                                 fmaxf(fmaxf(e[0], e[1]), mrun[it]));
            }
        };

        loadK(0, kA0, kA1);
#pragma unroll 1
        for (int tp = 0; tp < 16; ++tp) {
            const int t = 2 * tp;
            loadK(t + 1, kB0, kB1);
            step(kA0, kA1);
            loadK(t + 2, kA0, kA1);
            step(kB0, kB1);
        }

        // reduce across g (lanes lr, lr+16, lr+32, lr+48), then across waves via LDS
#pragma unroll
        for (int it = 0; it < 4; ++it) {
            float m = mrun[it];
#pragma unroll
            for (int mask = 16; mask < 64; mask <<= 1)
                m = fmaxf(m, __shfl_xor(m, mask, 64));
            if (g == 0)
                lmw[w * 64 + it * 16 + lr] = m;
        }
        __syncthreads();

        if (tid < 64) {
            float mm = lmw[tid];
#pragma unroll
            for (int w2 = 1; w2 < 8; ++w2) mm = fmaxf(mm, lmw[w2 * 64 + tid]);
            mfin[tid] = mm;
        }
        __syncthreads();
    }

    // m for row i = ib + it*16 + lr
    float mreg[4];
#pragma unroll
    for (int it = 0; it < 4; ++it)
        mreg[it] = mfin[it * 16 + lr];

    // ======== PASS 2: flash PV (R16 schedule) + l accumulation from f32 exps ========
    f32x4 acc[4][4];
#pragma unroll
    for (int it = 0; it < 4; ++it)
#pragma unroll
        for (int ct = 0; ct < 4; ++ct) {
            f32x4 z = {0.f, 0.f, 0.f, 0.f};
            acc[it][ct] = z;
        }

    float lrun[4] = {0.f, 0.f, 0.f, 0.f};   // per-lane partial sums of exp (f32)
    f16x8 vA[2][4], vB[2][4];   // half-chunk V buffers (ks 0-1 / ks 2-3), 32 VGPR each

    // frag-ordered V read: fully coalesced (uniform base + lane*16B)
    auto loadVh = [&](int t, int h, f16x8 (&vr)[2][4]) {
        const int tc = (t < 32) ? t : 31;
        const _Float16* base = vbw + (size_t)tc * 8192 + lane * 8;
#pragma unroll
        for (int ks2 = 0; ks2 < 2; ++ks2)
#pragma unroll
            for (int ct = 0; ct < 4; ++ct)
                vr[ks2][ct] = *reinterpret_cast<const f16x8*>(
                    base + (2 * h + ks2) * 2048 + ct * 512);
    };
    // E phase (SWAPPED): lane lr holds row i = it*16+lr, cols j = w*16+4g+{0..3}
    // -> one packed f16x4 LDS write per it. live=false for the tail-clamped duplicate
    // call (chunk index 32) so l isn't double-counted.
    auto ephase = [&](const f16x8& k0, const f16x8& k1, char* dst, bool live) {
#pragma unroll
        for (int it = 0; it < 4; ++it) {
            f32x4 e = {0.f, 0.f, 0.f, 0.f};
            e = __builtin_amdgcn_mfma_f32_16x16x32_f16(k0, qf[it][0], e, 0, 0, 0);
            e = __builtin_amdgcn_mfma_f32_16x16x32_f16(k1, qf[it][1], e, 0, 0, 0);
            float x0 = exp2f((e[0] - mreg[it]) * L2E);
            float x1 = exp2f((e[1] - mreg[it]) * L2E);
            float x2 = exp2f((e[2] - mreg[it]) * L2E);
            float x3 = exp2f((e[3] - mreg[it]) * L2E);
            if (live)
                lrun[it] += (x0 + x1) + (x2 + x3);
            f16x4 p;
            p[0] = (_Float16)x0; p[1] = (_Float16)x1;
            p[2] = (_Float16)x2; p[3] = (_Float16)x3;
            const int i   = it * 16 + lr;
            const int off = (i * 256 + (w * 32 + 8 * g)) ^ ((i & 15) << 4);
            *reinterpret_cast<f16x4*>(dst + off) = p;
        }
    };
    auto pvhalf = [&](const char* src, int h, const f16x8 (&vr)[2][4]) {
        __builtin_amdgcn_s_setprio(1);
#pragma unroll
        for (int ks2 = 0; ks2 < 2; ++ks2) {
            const int ks = 2 * h + ks2;
            f16x8 pa[4];
#pragma unroll
            for (int it = 0; it < 4; ++it) {
                const int off = (it * 16 + lr) * 256 + ((ks * 64 + g * 16) ^ (lr << 4));
                pa[it] = *reinterpret_cast<const f16x8*>(src + off);
            }
#pragma unroll
            for (int it = 0; it < 4; ++it)
#pragma unroll
                for (int ct = 0; ct < 4; ++ct)
                    acc[it][ct] = __builtin_amdgcn_mfma_f32_16x16x32_f16(pa[it], vr[ks2][ct], acc[it][ct], 0, 0, 0);
        }
        __builtin_amdgcn_s_setprio(0);
    };

    auto region = [&](int t, char* rbuf, char* wbuf, f16x8& ku0, f16x8& ku1,
                      f16x8& kl0, f16x8& kl1) {
        ephase(ku0, ku1, wbuf, (t + 1) < 32);   // P(t+1) using K(t+1)
        loadK(t + 2, kl0, kl1);                 // K(t+2) into the other slot
        pvhalf(rbuf, 0, vA);                    // PV(t) ks 0-1
        loadVh(t + 1, 0, vA);                   // V(t+1) ks 0-1
        pvhalf(rbuf, 1, vB);                    // PV(t) ks 2-3
        loadVh(t + 1, 1, vB);                   // V(t+1) ks 2-3
        LDS_BARRIER();
    };

    // Prologue: P(0) -> pb0, V(0) -> vA/vB, K(1) -> kA.
    loadK(0, kA0, kA1);
    loadVh(0, 0, vA);
    loadVh(0, 1, vB);
    ephase(kA0, kA1, pb0, true);        // P(0) (uses K(0) in kA)
    loadK(1, kA0, kA1);                 // K(1) -> kA (K(0) dead)
    __syncthreads();

#pragma unroll 1
    for (int tp = 0; tp < 16; ++tp) {
        const int t = 2 * tp;
        region(t,     pb0, pb1, kA0, kA1, kB0, kB1);   // chunk t:   P in pb0, K(t+1)=kA
        region(t + 1, pb1, pb0, kB0, kB1, kA0, kA1);   // chunk t+1: P in pb1, K(t+2)=kB
    }
    // (final region's ephase is live=false; all 32 chunks PV'd and l-counted once)

    // ---- reduce l across g and waves ----
#pragma unroll
    for (int it = 0; it < 4; ++it) {
        float s = lrun[it];
#pragma unroll
        for (int mask = 16; mask < 64; mask <<= 1)
            s += __shfl_xor(s, mask, 64);
        if (g == 0)
            lmw[w * 64 + it * 16 + lr] = s;
    }
    __syncthreads();
    if (tid < 64) {
        float ss = 0.f;
#pragma unroll
        for (int w2 = 0; w2 < 8; ++w2) ss += lmw[w2 * 64 + tid];
        lfin[tid] = ss;
    }
    __syncthreads();

    // ---- epilogue: out = gamma * acc / l + x (l from LDS) ----
    const float gm = gamma[0];
#pragma unroll
    for (int it = 0; it < 4; ++it) {
        const int rb = it * 16 + 4 * g;     // local row base for this lane's acc
        const int idx = ib + rb;
        float inv[4];
#pragma unroll
        for (int r = 0; r < 4; ++r)
            inv[r] = 1.0f / lfin[rb + r];
#pragma unroll
        for (int ct = 0; ct < 4; ++ct) {
            const int c = cw + ct * 16 + lr;
            const size_t base = (size_t)(b * CDIM + c) * NPOS + idx;
            const float4 xv = *reinterpret_cast<const float4*>(x + base);
            float4 ov;
            ov.x = gm * (acc[it][ct][0] * inv[0]) + xv.x;
            ov.y = gm * (acc[it][ct][1] * inv[1]) + xv.y;
            ov.z = gm * (acc[it][ct][2] * inv[2]) + xv.z;
            ov.w = gm * (acc[it][ct][3] * inv[3]) + xv.w;
            *reinterpret_cast<float4*>(out + base) = ov;
        }
    }
}

extern "C" void kernel_launch(void* const* d_in, const int* in_sizes, int n_in,
                              void* d_out, int out_size, void* d_ws, size_t ws_size,
                              hipStream_t stream)
{
    (void)in_sizes; (void)n_in; (void)out_size; (void)ws_size;

    const float* x     = (const float*)d_in[0];
    const float* wq    = (const float*)d_in[1];
    const float* bq    = (const float*)d_in[2];
    const float* wk    = (const float*)d_in[3];
    const float* bk    = (const float*)d_in[4];
    const float* wv    = (const float*)d_in[5];
    const float* bv    = (const float*)d_in[6];
    const float* gamma = (const float*)d_in[7];
    float* out = (float*)d_out;

    char* ws = (char*)d_ws;
    const size_t qkBytes = (size_t)NBATCH * NPOS * CQK * sizeof(_Float16);     //  2 MiB each (K frag-ordered, same size)
    const size_t vBytes  = (size_t)NBATCH * CDIM * NPOS * sizeof(_Float16);    // 16 MiB (frag-ordered)
    const size_t xtBytes = (size_t)NBATCH * NPOS * CDIM * sizeof(_Float16);    // 16 MiB

    _Float16* Qp = (_Float16*)(ws);
    _Float16* Kp = (_Float16*)(ws + qkBytes);
    _Float16* Vp = (_Float16*)(ws + 2 * qkBytes);
    _Float16* Xt = (_Float16*)(ws + 2 * qkBytes + vBytes);
    _Float16* Wh = (_Float16*)(ws + 2 * qkBytes + vBytes + xtBytes);
    float* biasc = (float*)(ws + 2 * qkBytes + vBytes + xtBytes
                              + (size_t)640 * CDIM * sizeof(_Float16));
    // total ws use ~= 36.6 MiB

    x_cvt_kernel<<<dim3(NPOS / 64, CDIM / 64, NBATCH), 256, 0, stream>>>(
        x, Xt, wq, bq, wk, bk, wv, bv, Wh, biasc);
    proj_gemm_kernel<<<dim3(NPOS / 128, 5, NBATCH), 256, 0, stream>>>(Wh, biasc, Xt, Qp, Kp, Vp);
    attn_fused_kernel<<<dim3(NPOS / 64 * NBATCH), 512, 0, stream>>>(x, Qp, Kp, Vp, gamma, out);
}